// Round 2
// baseline (3845.021 us; speedup 1.0000x reference)
//
#include <hip/hip_runtime.h>

// Problem constants (fixed by the reference): B=1
#define S_DIM 128
#define L_DIM 256
#define D_DIM 768
#define H_DIM 12
#define TD    2304            // 3*D
#define NROW  32768           // S*L
#define LN_EPS 1e-5f

typedef unsigned short u16;
typedef unsigned int   u32;

// Workspace layout (bytes):
//   p      : fp16 [NROW][TD]            = 150,994,944
//   logits : f32  [H][L][L]             =   3,145,728
//   out1   : f32  [NROW][D]             = 100,663,296
// total ~243 MiB. d_out is additionally used as scratch for row_out/col_out.
#define WS_P_OFF      0
#define WS_LOGITS_OFF 150994944
#define WS_OUT1_OFF   154140672

// fp16 staging (NOT bf16): row logits accumulate K=8192 products; bf16's
// 2^-9 rel-err gave logit rms err ~0.045 -> final absmax 0.15 > 0.113 thr.
// fp16 cuts that 8x. All values |.|<10, far from fp16 range limits.
__device__ __forceinline__ float h2f(u16 v) {
    union { u16 u; _Float16 h; } c; c.u = v; return (float)c.h;
}
__device__ __forceinline__ u16 f2h(float f) {
    union { u16 u; _Float16 h; } c; c.h = (_Float16)f; return c.u;   // RNE
}

// ---------------------------------------------------------------------------
// C[n,m] = sum_k A[n,k]*W[m,k] + bias[m]   (A:[N,K] f32, W:[M,K] f32, C fp16)
// 128x128 tile, BK=16, 256 threads, 8x8 micro-tile. grid (M/128, N/128).
// ---------------------------------------------------------------------------
__global__ __launch_bounds__(256)
void gemm_nt_bias_f16(const float* __restrict__ A, const float* __restrict__ W,
                      const float* __restrict__ bias, u16* __restrict__ C,
                      int N, int M, int K)
{
    __shared__ float As[16][132];   // [k][row], pad 132 keeps float4 alignment
    __shared__ float Ws[16][132];
    const int tid = threadIdx.x;
    const int tx = tid & 15, ty = tid >> 4;
    const int n0 = blockIdx.y * 128, m0 = blockIdx.x * 128;
    const int lrow = tid >> 1;           // 0..127
    const int lk   = (tid & 1) * 8;      // 0 or 8

    float acc[8][8];
#pragma unroll
    for (int i = 0; i < 8; ++i)
#pragma unroll
        for (int j = 0; j < 8; ++j) acc[i][j] = 0.f;

    const float* Aptr = A + (size_t)(n0 + lrow) * K + lk;
    const float* Wptr = W + (size_t)(m0 + lrow) * K + lk;

    for (int k0 = 0; k0 < K; k0 += 16) {
        float4 a0 = *(const float4*)(Aptr + k0);
        float4 a1 = *(const float4*)(Aptr + k0 + 4);
        float4 w0 = *(const float4*)(Wptr + k0);
        float4 w1 = *(const float4*)(Wptr + k0 + 4);
        __syncthreads();
        As[lk+0][lrow] = a0.x; As[lk+1][lrow] = a0.y; As[lk+2][lrow] = a0.z; As[lk+3][lrow] = a0.w;
        As[lk+4][lrow] = a1.x; As[lk+5][lrow] = a1.y; As[lk+6][lrow] = a1.z; As[lk+7][lrow] = a1.w;
        Ws[lk+0][lrow] = w0.x; Ws[lk+1][lrow] = w0.y; Ws[lk+2][lrow] = w0.z; Ws[lk+3][lrow] = w0.w;
        Ws[lk+4][lrow] = w1.x; Ws[lk+5][lrow] = w1.y; Ws[lk+6][lrow] = w1.z; Ws[lk+7][lrow] = w1.w;
        __syncthreads();
#pragma unroll
        for (int kk = 0; kk < 16; ++kk) {
            float4 av0 = *(const float4*)&As[kk][ty*8];
            float4 av1 = *(const float4*)&As[kk][ty*8+4];
            float4 wv0 = *(const float4*)&Ws[kk][tx*8];
            float4 wv1 = *(const float4*)&Ws[kk][tx*8+4];
            float a[8] = {av0.x,av0.y,av0.z,av0.w,av1.x,av1.y,av1.z,av1.w};
            float w[8] = {wv0.x,wv0.y,wv0.z,wv0.w,wv1.x,wv1.y,wv1.z,wv1.w};
#pragma unroll
            for (int i = 0; i < 8; ++i)
#pragma unroll
                for (int j = 0; j < 8; ++j)
                    acc[i][j] += a[i] * w[j];
        }
    }

    float bv[8];
#pragma unroll
    for (int j = 0; j < 8; ++j) bv[j] = bias[m0 + tx*8 + j];
#pragma unroll
    for (int i = 0; i < 8; ++i) {
        u16* crow = C + (size_t)(n0 + ty*8 + i) * M + m0 + tx*8;
        ushort4 s0, s1;
        s0.x = f2h(acc[i][0] + bv[0]); s0.y = f2h(acc[i][1] + bv[1]);
        s0.z = f2h(acc[i][2] + bv[2]); s0.w = f2h(acc[i][3] + bv[3]);
        s1.x = f2h(acc[i][4] + bv[4]); s1.y = f2h(acc[i][5] + bv[5]);
        s1.z = f2h(acc[i][6] + bv[6]); s1.w = f2h(acc[i][7] + bv[7]);
        *(ushort4*)(crow)     = s0;
        *(ushort4*)(crow + 4) = s1;
    }
}

// ---------------------------------------------------------------------------
// logits[h][i][j] = sum_{s,c} q[s,i,h,c]*k[s,j,h,c]
// grid (L/32, L/32, H); 256 threads; 2x2 micro-tile; c-major LDS for b64 reads
// ---------------------------------------------------------------------------
__global__ __launch_bounds__(256)
void row_logits(const u16* __restrict__ p, float* __restrict__ logits)
{
    __shared__ float Qs[64][34];   // [c][i], pad 34 keeps float2 alignment
    __shared__ float Ks[64][34];   // [c][j]
    const int tid = threadIdx.x;
    const int tx = tid & 15, ty = tid >> 4;
    const int i0 = blockIdx.x * 32, j0 = blockIdx.y * 32;
    const int h = blockIdx.z;
    const int lr = tid >> 3;          // 0..31
    const int lc = (tid & 7) * 8;     // 0..56
    float acc[2][2] = {{0.f,0.f},{0.f,0.f}};

    for (int s = 0; s < S_DIM; ++s) {
        union { float4 f; u16 u[8]; } qa, ka;
        qa.f = *(const float4*)(p + ((size_t)(s * L_DIM + i0 + lr)) * TD + h*64 + lc);
        ka.f = *(const float4*)(p + ((size_t)(s * L_DIM + j0 + lr)) * TD + 768 + h*64 + lc);
        __syncthreads();
#pragma unroll
        for (int e = 0; e < 8; ++e) {
            Qs[lc+e][lr] = h2f(qa.u[e]);
            Ks[lc+e][lr] = h2f(ka.u[e]);
        }
        __syncthreads();
#pragma unroll
        for (int c = 0; c < 64; ++c) {
            float2 qv = *(const float2*)&Qs[c][ty*2];
            float2 kv = *(const float2*)&Ks[c][tx*2];
            acc[0][0] += qv.x * kv.x;
            acc[0][1] += qv.x * kv.y;
            acc[1][0] += qv.y * kv.x;
            acc[1][1] += qv.y * kv.y;
        }
    }
#pragma unroll
    for (int a = 0; a < 2; ++a)
#pragma unroll
        for (int b = 0; b < 2; ++b)
            logits[((size_t)h * L_DIM + i0 + ty*2 + a) * L_DIM + (j0 + tx*2 + b)] = acc[a][b];
}

// ---------------------------------------------------------------------------
// In-place softmax over rows of 256. grid = H*L, block 256.
// ---------------------------------------------------------------------------
__global__ __launch_bounds__(256)
void softmax256(float* __restrict__ logits)
{
    __shared__ float red[256];
    const int t = threadIdx.x;
    float* row = logits + (size_t)blockIdx.x * 256;
    float v = row[t];
    red[t] = v; __syncthreads();
    for (int w = 128; w > 0; w >>= 1) { if (t < w) red[t] = fmaxf(red[t], red[t+w]); __syncthreads(); }
    float m = red[0];
    __syncthreads();
    float e = __expf(v - m);
    red[t] = e; __syncthreads();
    for (int w = 128; w > 0; w >>= 1) { if (t < w) red[t] += red[t+w]; __syncthreads(); }
    row[t] = e / red[0];
}

// ---------------------------------------------------------------------------
// rout[(s*L+i)*D + h*64 + d] = sum_j attn[h][i][j] * v[s,j,h,d]
// grid (L/32, H, S); 256 threads; 2(i) x 4(d) micro-tile; K-tile 32 over j.
// ---------------------------------------------------------------------------
__global__ __launch_bounds__(256)
void row_pv(const float* __restrict__ attn, const u16* __restrict__ p,
            float* __restrict__ rout)
{
    __shared__ float Ps[32][33];
    __shared__ float Vs[32][68];
    const int tid = threadIdx.x;
    const int tx = tid & 15, ty = tid >> 4;
    const int i0 = blockIdx.x * 32;
    const int h  = blockIdx.y;
    const int s  = blockIdx.z;
    const float* arow = attn + ((size_t)h * L_DIM + i0) * L_DIM;
    const int pr = tid >> 3, pc = (tid & 7) * 4;
    const int vr = tid >> 3, vc = (tid & 7) * 8;
    float acc[2][4] = {{0.f,0.f,0.f,0.f},{0.f,0.f,0.f,0.f}};

    for (int j0 = 0; j0 < L_DIM; j0 += 32) {
        float4 pv = *(const float4*)(arow + (size_t)pr * L_DIM + j0 + pc);
        union { float4 f; u16 u[8]; } vv;
        vv.f = *(const float4*)(p + ((size_t)(s * L_DIM + j0 + vr)) * TD + 1536 + h*64 + vc);
        __syncthreads();
        Ps[pr][pc+0] = pv.x; Ps[pr][pc+1] = pv.y; Ps[pr][pc+2] = pv.z; Ps[pr][pc+3] = pv.w;
#pragma unroll
        for (int e = 0; e < 8; ++e) Vs[vr][vc+e] = h2f(vv.u[e]);
        __syncthreads();
#pragma unroll
        for (int jj = 0; jj < 32; ++jj) {
            float p0 = Ps[ty*2+0][jj];
            float p1 = Ps[ty*2+1][jj];
            float4 v4 = *(const float4*)&Vs[jj][tx*4];
            acc[0][0] += p0*v4.x; acc[0][1] += p0*v4.y; acc[0][2] += p0*v4.z; acc[0][3] += p0*v4.w;
            acc[1][0] += p1*v4.x; acc[1][1] += p1*v4.y; acc[1][2] += p1*v4.z; acc[1][3] += p1*v4.w;
        }
    }
#pragma unroll
    for (int a = 0; a < 2; ++a) {
        float4 o; o.x = acc[a][0]; o.y = acc[a][1]; o.z = acc[a][2]; o.w = acc[a][3];
        *(float4*)(rout + ((size_t)(s * L_DIM + i0 + ty*2 + a)) * D_DIM + h*64 + tx*4) = o;
    }
}

// ---------------------------------------------------------------------------
// out[n,:] = LN(x[n,:] + r[n,:]) * g + beta.  grid = NROW, block 256.
// Safe when out == r (each thread reads its elements before writing them).
// ---------------------------------------------------------------------------
__global__ __launch_bounds__(256)
void add_ln(const float* __restrict__ x, const float* __restrict__ r,
            const float* __restrict__ g, const float* __restrict__ beta,
            float* __restrict__ out)
{
    __shared__ float red[256];
    const int n = blockIdx.x, t = threadIdx.x;
    const float* xp = x + (size_t)n * D_DIM;
    const float* rp = r + (size_t)n * D_DIM;
    float v[3]; float s = 0.f;
#pragma unroll
    for (int e = 0; e < 3; ++e) { v[e] = xp[t + e*256] + rp[t + e*256]; s += v[e]; }
    red[t] = s; __syncthreads();
    for (int w = 128; w > 0; w >>= 1) { if (t < w) red[t] += red[t+w]; __syncthreads(); }
    float mean = red[0] * (1.f/768.f);
    __syncthreads();
    float sq = 0.f;
#pragma unroll
    for (int e = 0; e < 3; ++e) { float d = v[e] - mean; sq += d*d; }
    red[t] = sq; __syncthreads();
    for (int w = 128; w > 0; w >>= 1) { if (t < w) red[t] += red[t+w]; __syncthreads(); }
    float rstd = rsqrtf(red[0] * (1.f/768.f) + LN_EPS);
#pragma unroll
    for (int e = 0; e < 3; ++e) {
        int idx = t + e*256;
        out[(size_t)n * D_DIM + idx] = (v[e] - mean) * rstd * g[idx] + beta[idx];
    }
}

// ---------------------------------------------------------------------------
// Fused column attention for one (l, h, i-half): q/k/v from p_col (fp16).
//   P[j][i] = sum_c q[i,l,h,c]*k[j,l,h,c]; softmax over j; out = P^T V.
// grid (L, H, S/64); 256 threads. LDS < 64 KB (58.9 KB).
// ---------------------------------------------------------------------------
__global__ __launch_bounds__(256)
void col_attn(const u16* __restrict__ p, float* __restrict__ cout)
{
    __shared__ float smem_f[14976];                 // 59,904 B
    u16* Qs = (u16*)smem_f;                         // [64][68]  c-major: Qs[c*68+i]
    u16* Ks = (u16*)((char*)smem_f + 8704);         // [64][132] c-major: Ks[c*132+j]
    u16* Vs = (u16*)smem_f;                         // overlay [128][68]: Vs[j*68+d]
    float* P = smem_f + 6400;                       // [128][67] transposed: P[j*67+i]

    const int tid = threadIdx.x;
    const int l = blockIdx.x, h = blockIdx.y;
    const int i0g = blockIdx.z * 64;

    // phase 1: load Q (64 i x 64 c) and K (128 j x 64 c), fp16, transposed to c-major
    {
        int qi = tid >> 2, qc = (tid & 3) * 16;
        const u16* qp = p + ((size_t)((i0g + qi) * L_DIM + l)) * TD + h*64 + qc;
        union { float4 f; u16 u[8]; } b0, b1;
        b0.f = *(const float4*)qp; b1.f = *(const float4*)(qp + 8);
#pragma unroll
        for (int e = 0; e < 8; ++e) {
            Qs[(qc+e)*68 + qi]   = b0.u[e];
            Qs[(qc+8+e)*68 + qi] = b1.u[e];
        }
        int kj = tid >> 1, kc = (tid & 1) * 32;
        const u16* kp = p + ((size_t)(kj * L_DIM + l)) * TD + 768 + h*64 + kc;
#pragma unroll
        for (int q = 0; q < 4; ++q) {
            union { float4 f; u16 u[8]; } kb;
            kb.f = *(const float4*)(kp + q*8);
#pragma unroll
            for (int e = 0; e < 8; ++e) Ks[(kc + q*8 + e)*132 + kj] = kb.u[e];
        }
    }
    __syncthreads();

    // phase 2: P[j][i] = sum_c Q[i][c]*K[j][c]; 4(i) x 8(j) per thread
    {
        const int tx = tid & 15, ty = tid >> 4;
        const int jb = tx * 8, ib = ty * 4;
        float acc[4][8];
#pragma unroll
        for (int a = 0; a < 4; ++a)
#pragma unroll
            for (int b = 0; b < 8; ++b) acc[a][b] = 0.f;
        for (int c = 0; c < 64; ++c) {
            ushort4 qr = *(const ushort4*)&Qs[c*68 + ib];
            float qf[4] = {h2f(qr.x), h2f(qr.y), h2f(qr.z), h2f(qr.w)};
            union { float4 f; u16 u[8]; } kr;
            kr.f = *(const float4*)&Ks[c*132 + jb];
            float kf[8];
#pragma unroll
            for (int b = 0; b < 8; ++b) kf[b] = h2f(kr.u[b]);
#pragma unroll
            for (int a = 0; a < 4; ++a)
#pragma unroll
                for (int b = 0; b < 8; ++b)
                    acc[a][b] += qf[a] * kf[b];
        }
#pragma unroll
        for (int a = 0; a < 4; ++a)
#pragma unroll
            for (int b = 0; b < 8; ++b)
                P[(jb + b)*67 + ib + a] = acc[a][b];
    }
    __syncthreads();

    // phase 3: load V (overlays Q/K region — phase 2 is done with it)
    {
        int vj = tid >> 1, vd = (tid & 1) * 32;
        const u16* vp = p + ((size_t)(vj * L_DIM + l)) * TD + 1536 + h*64 + vd;
#pragma unroll
        for (int q = 0; q < 4; ++q) {
            union { float4 f; ushort4 h2v[2]; } vb;
            vb.f = *(const float4*)(vp + q*8);
            *(ushort4*)&Vs[vj*68 + vd + q*8]     = vb.h2v[0];
            *(ushort4*)&Vs[vj*68 + vd + q*8 + 4] = vb.h2v[1];
        }
    }
    __syncthreads();

    // phase 4: softmax over j for each local i (one wave, one row per lane)
    if (tid < 64) {
        float m = -1e30f;
        for (int j = 0; j < 128; ++j) m = fmaxf(m, P[j*67 + tid]);
        float sum = 0.f;
        for (int j = 0; j < 128; ++j) {
            float e = __expf(P[j*67 + tid] - m);
            P[j*67 + tid] = e; sum += e;
        }
        float inv = 1.f / sum;
        for (int j = 0; j < 128; ++j) P[j*67 + tid] *= inv;
    }
    __syncthreads();

    // phase 5: out[i][d] = sum_j P[j][i]*V[j][d]; 1 i x 16 d per thread
    {
        int i = tid >> 2, dq = (tid & 3) * 16;
        float acc[16];
#pragma unroll
        for (int q = 0; q < 16; ++q) acc[q] = 0.f;
        for (int j = 0; j < 128; ++j) {
            float pw = P[j*67 + i];
#pragma unroll
            for (int q = 0; q < 4; ++q) {
                ushort4 v4 = *(const ushort4*)&Vs[j*68 + dq + q*4];
                acc[q*4+0] += pw * h2f(v4.x);
                acc[q*4+1] += pw * h2f(v4.y);
                acc[q*4+2] += pw * h2f(v4.z);
                acc[q*4+3] += pw * h2f(v4.w);
            }
        }
        float* op = cout + ((size_t)((i0g + i) * L_DIM + l)) * D_DIM + h*64 + dq;
#pragma unroll
        for (int q = 0; q < 4; ++q) {
            float4 o; o.x = acc[q*4+0]; o.y = acc[q*4+1]; o.z = acc[q*4+2]; o.w = acc[q*4+3];
            *(float4*)(op + q*4) = o;
        }
    }
}

// ---------------------------------------------------------------------------
extern "C" void kernel_launch(void* const* d_in, const int* in_sizes, int n_in,
                              void* d_out, int out_size, void* d_ws, size_t ws_size,
                              hipStream_t stream)
{
    const float* x     = (const float*)d_in[0];
    const float* w_row = (const float*)d_in[1];
    const float* b_row = (const float*)d_in[2];
    const float* w_col = (const float*)d_in[3];
    const float* b_col = (const float*)d_in[4];
    const float* g1    = (const float*)d_in[5];
    const float* be1   = (const float*)d_in[6];
    const float* g2    = (const float*)d_in[7];
    const float* be2   = (const float*)d_in[8];
    float* out = (float*)d_out;

    char* ws = (char*)d_ws;
    u16*   p      = (u16*)(ws + WS_P_OFF);
    float* logits = (float*)(ws + WS_LOGITS_OFF);
    float* out1   = (float*)(ws + WS_OUT1_OFF);

    // 1) row QKV projection -> p (fp16)
    gemm_nt_bias_f16<<<dim3(TD/128, NROW/128), 256, 0, stream>>>(x, w_row, b_row, p, NROW, TD, D_DIM);
    // 2) tied row logits
    row_logits<<<dim3(L_DIM/32, L_DIM/32, H_DIM), 256, 0, stream>>>(p, logits);
    // 3) softmax over j
    softmax256<<<H_DIM * L_DIM, 256, 0, stream>>>(logits);
    // 4) row PV -> d_out (scratch)
    row_pv<<<dim3(L_DIM/32, H_DIM, S_DIM), 256, 0, stream>>>(logits, p, out);
    // 5) out1 = LN(x + row_out)
    add_ln<<<NROW, 256, 0, stream>>>(x, out, g1, be1, out1);
    // 6) col QKV projection -> p (fp16, reuse buffer)
    gemm_nt_bias_f16<<<dim3(TD/128, NROW/128), 256, 0, stream>>>(out1, w_col, b_col, p, NROW, TD, D_DIM);
    // 7) fused column attention -> d_out (scratch)
    col_attn<<<dim3(L_DIM, H_DIM, S_DIM/64), 256, 0, stream>>>(p, out);
    // 8) out = LN(out1 + col_out), in place on d_out
    add_ln<<<NROW, 256, 0, stream>>>(out1, out, g2, be2, out);
}

// Round 3
// 1612.380 us; speedup vs baseline: 2.3847x; 2.3847x over previous
//
#include <hip/hip_runtime.h>

// Problem constants (fixed by the reference): B=1
#define S_DIM 128
#define L_DIM 256
#define D_DIM 768
#define H_DIM 12
#define TD    2304            // 3*D
#define NROW  32768           // S*L
#define KDIM  768
#define LN_EPS 1e-5f

typedef unsigned short u16;
typedef unsigned int   u32;
typedef _Float16 f16;
typedef _Float16 f16x8 __attribute__((ext_vector_type(8)));
typedef _Float16 f16x4 __attribute__((ext_vector_type(4)));
typedef float    f32x4 __attribute__((ext_vector_type(4)));

// Workspace layout (bytes), total 211,550,208 (< 255 MB proven in round 2):
//   p      : f16 [NROW][TD]   150,994,944
//   logits : f32 [H][L][L]      3,145,728
//   xh/u1h : f16 [NROW][D]     50,331,648  (xh dead after GEMM1; out1_h written step 5)
//   wr_h   : f16 [TD][D]        3,538,944
//   wc_h   : f16 [TD][D]        3,538,944
#define WS_P_OFF      0
#define WS_LOGITS_OFF 150994944
#define WS_XH_OFF     154140672
#define WS_WRH_OFF    204472320
#define WS_WCH_OFF    208011264

// fp16 staging (NOT bf16): row logits accumulate K=8192 products; bf16's
// 2^-9 rel-err gave final absmax 0.15 > 0.113 thr (round 1). fp16 passes
// at 0.031 (round 2); fp16 MFMA inputs add ~sqrt(3)x -> ~0.05, still safe.
__device__ __forceinline__ float h2f(u16 v) {
    union { u16 u; f16 h; } c; c.u = v; return (float)c.h;
}
__device__ __forceinline__ u16 f2h(float f) {
    union { u16 u; f16 h; } c; c.h = (f16)f; return c.u;   // RNE
}

__device__ __forceinline__ void gload_lds16(const void* g, void* l) {
    __builtin_amdgcn_global_load_lds((const __attribute__((address_space(1))) void*)g,
                                     (__attribute__((address_space(3))) void*)l, 16, 0, 0);
}

// ---------------------------------------------------------------------------
// f32 -> f16 convert, 4 elems/thread, grid sized exactly (n % 1024 == 0).
// ---------------------------------------------------------------------------
__global__ __launch_bounds__(256)
void cvt_f32_f16(const float* __restrict__ in, f16* __restrict__ out)
{
    int i = blockIdx.x * 256 + threadIdx.x;
    float4 v = ((const float4*)in)[i];
    f16x4 o; o.x = (f16)v.x; o.y = (f16)v.y; o.z = (f16)v.z; o.w = (f16)v.w;
    ((f16x4*)out)[i] = o;
}

// ---------------------------------------------------------------------------
// MFMA GEMM: C[n,m] = sum_k A[n,k]*W[m,k] + bias[m]; A,W f16 K-major, C f16.
// N=32768, M=TD=2304, K=768 hardcoded. 128x128 tile, BK=32, 256 thr = 4 waves
// (2x2 of 64x64), each wave 4x4 of mfma_f32_16x16x32_f16. Staging via
// global_load_lds width=16 (lane-contiguous dest => no pad possible); LDS
// chunk swizzle j ^= (m>>1)&3 makes frag ds_read_b128 2-way (free, m136).
// grid (TD/128=18, NROW/128=256).
// ---------------------------------------------------------------------------
__global__ __launch_bounds__(256)
void mfma_gemm_qkv(const f16* __restrict__ A, const f16* __restrict__ W,
                   const float* __restrict__ bias, f16* __restrict__ C)
{
    __shared__ f16 As[128 * 32];   // 8 KB, 512 chunks of 16 B
    __shared__ f16 Bs[128 * 32];
    const int tid  = threadIdx.x;
    const int lane = tid & 63;
    const int w    = tid >> 6;
    const int wr   = (w >> 1) * 64;    // wave row offset in tile
    const int wc   = (w & 1) * 64;     // wave col offset in tile
    const int lm   = lane & 15;
    const int q    = lane >> 4;        // quad: k-chunk of the fragment
    const int row0 = blockIdx.y * 128;
    const int col0 = blockIdx.x * 128;

    // staging source offsets (k0-independent): wave w owns chunks
    // [w*128, w*128+128); chunk c -> row m=c>>2, lds j=c&3, global chunk
    // gj = j ^ ((m>>1)&3).
    size_t soff[2];
    int    ldsc[2];
#pragma unroll
    for (int t = 0; t < 2; ++t) {
        int c  = w * 128 + t * 64 + lane;
        int m  = c >> 2;
        int gj = (c & 3) ^ ((m >> 1) & 3);
        soff[t] = (size_t)m * KDIM + gj * 8;
        ldsc[t] = (w * 128 + t * 64) * 8;     // f16 elems
    }
    const f16* baseA = A + (size_t)row0 * KDIM;
    const f16* baseB = W + (size_t)col0 * KDIM;

    // fragment LDS chunk ids (k0-independent)
    int chA[4], chB[4];
#pragma unroll
    for (int t = 0; t < 4; ++t) {
        int ma = wr + t * 16 + lm;
        chA[t] = ma * 4 + (q ^ ((ma >> 1) & 3));
        int mb = wc + t * 16 + lm;
        chB[t] = mb * 4 + (q ^ ((mb >> 1) & 3));
    }

    f32x4 acc[4][4];
#pragma unroll
    for (int i = 0; i < 4; ++i)
#pragma unroll
        for (int j = 0; j < 4; ++j) acc[i][j] = (f32x4)0.f;

    for (int k0 = 0; k0 < KDIM; k0 += 32) {
#pragma unroll
        for (int t = 0; t < 2; ++t) {
            gload_lds16(baseA + soff[t] + k0, &As[ldsc[t]]);
            gload_lds16(baseB + soff[t] + k0, &Bs[ldsc[t]]);
        }
        __syncthreads();      // drain DMA (compiler emits vmcnt(0))
        f16x8 af[4], bf[4];
#pragma unroll
        for (int t = 0; t < 4; ++t) af[t] = *(const f16x8*)&As[chA[t] * 8];
#pragma unroll
        for (int t = 0; t < 4; ++t) bf[t] = *(const f16x8*)&Bs[chB[t] * 8];
#pragma unroll
        for (int mt = 0; mt < 4; ++mt)
#pragma unroll
            for (int nt = 0; nt < 4; ++nt)
                acc[mt][nt] = __builtin_amdgcn_mfma_f32_16x16x32_f16(
                    af[mt], bf[nt], acc[mt][nt], 0, 0, 0);
        __syncthreads();      // all frag reads done before next DMA overwrite
    }

    // epilogue: C/D layout col=lane&15, row=quad*4+reg
    float bv[4];
#pragma unroll
    for (int nt = 0; nt < 4; ++nt) bv[nt] = bias[col0 + wc + nt * 16 + lm];
#pragma unroll
    for (int mt = 0; mt < 4; ++mt) {
        int grow = row0 + wr + mt * 16 + q * 4;
#pragma unroll
        for (int nt = 0; nt < 4; ++nt) {
            int gcol = col0 + wc + nt * 16 + lm;
#pragma unroll
            for (int r = 0; r < 4; ++r)
                C[(size_t)(grow + r) * TD + gcol] = (f16)(acc[mt][nt][r] + bv[nt]);
        }
    }
}

// ---------------------------------------------------------------------------
// logits[h][i][j] = sum_{s,c} q[s,i,h,c]*k[s,j,h,c]
// grid (L/32, L/32, H); 256 threads; 2x2 micro-tile; c-major LDS
// ---------------------------------------------------------------------------
__global__ __launch_bounds__(256)
void row_logits(const u16* __restrict__ p, float* __restrict__ logits)
{
    __shared__ float Qs[64][34];
    __shared__ float Ks[64][34];
    const int tid = threadIdx.x;
    const int tx = tid & 15, ty = tid >> 4;
    const int i0 = blockIdx.x * 32, j0 = blockIdx.y * 32;
    const int h = blockIdx.z;
    const int lr = tid >> 3;
    const int lc = (tid & 7) * 8;
    float acc[2][2] = {{0.f,0.f},{0.f,0.f}};

    for (int s = 0; s < S_DIM; ++s) {
        union { float4 f; u16 u[8]; } qa, ka;
        qa.f = *(const float4*)(p + ((size_t)(s * L_DIM + i0 + lr)) * TD + h*64 + lc);
        ka.f = *(const float4*)(p + ((size_t)(s * L_DIM + j0 + lr)) * TD + 768 + h*64 + lc);
        __syncthreads();
#pragma unroll
        for (int e = 0; e < 8; ++e) {
            Qs[lc+e][lr] = h2f(qa.u[e]);
            Ks[lc+e][lr] = h2f(ka.u[e]);
        }
        __syncthreads();
#pragma unroll
        for (int c = 0; c < 64; ++c) {
            float2 qv = *(const float2*)&Qs[c][ty*2];
            float2 kv = *(const float2*)&Ks[c][tx*2];
            acc[0][0] += qv.x * kv.x;
            acc[0][1] += qv.x * kv.y;
            acc[1][0] += qv.y * kv.x;
            acc[1][1] += qv.y * kv.y;
        }
    }
#pragma unroll
    for (int a = 0; a < 2; ++a)
#pragma unroll
        for (int b = 0; b < 2; ++b)
            logits[((size_t)h * L_DIM + i0 + ty*2 + a) * L_DIM + (j0 + tx*2 + b)] = acc[a][b];
}

// ---------------------------------------------------------------------------
// In-place softmax over rows of 256. grid = H*L, block 256.
// ---------------------------------------------------------------------------
__global__ __launch_bounds__(256)
void softmax256(float* __restrict__ logits)
{
    __shared__ float red[256];
    const int t = threadIdx.x;
    float* row = logits + (size_t)blockIdx.x * 256;
    float v = row[t];
    red[t] = v; __syncthreads();
    for (int w = 128; w > 0; w >>= 1) { if (t < w) red[t] = fmaxf(red[t], red[t+w]); __syncthreads(); }
    float m = red[0];
    __syncthreads();
    float e = __expf(v - m);
    red[t] = e; __syncthreads();
    for (int w = 128; w > 0; w >>= 1) { if (t < w) red[t] += red[t+w]; __syncthreads(); }
    row[t] = e / red[0];
}

// ---------------------------------------------------------------------------
// rout[(s*L+i)*D + h*64 + d] = sum_j attn[h][i][j] * v[s,j,h,d]
// grid (L/32, H, S); 256 threads; 2(i) x 4(d) micro-tile; K-tile 32 over j.
// ---------------------------------------------------------------------------
__global__ __launch_bounds__(256)
void row_pv(const float* __restrict__ attn, const u16* __restrict__ p,
            float* __restrict__ rout)
{
    __shared__ float Ps[32][33];
    __shared__ float Vs[32][68];
    const int tid = threadIdx.x;
    const int tx = tid & 15, ty = tid >> 4;
    const int i0 = blockIdx.x * 32;
    const int h  = blockIdx.y;
    const int s  = blockIdx.z;
    const float* arow = attn + ((size_t)h * L_DIM + i0) * L_DIM;
    const int pr = tid >> 3, pc = (tid & 7) * 4;
    const int vr = tid >> 3, vc = (tid & 7) * 8;
    float acc[2][4] = {{0.f,0.f,0.f,0.f},{0.f,0.f,0.f,0.f}};

    for (int j0 = 0; j0 < L_DIM; j0 += 32) {
        float4 pv = *(const float4*)(arow + (size_t)pr * L_DIM + j0 + pc);
        union { float4 f; u16 u[8]; } vv;
        vv.f = *(const float4*)(p + ((size_t)(s * L_DIM + j0 + vr)) * TD + 1536 + h*64 + vc);
        __syncthreads();
        Ps[pr][pc+0] = pv.x; Ps[pr][pc+1] = pv.y; Ps[pr][pc+2] = pv.z; Ps[pr][pc+3] = pv.w;
#pragma unroll
        for (int e = 0; e < 8; ++e) Vs[vr][vc+e] = h2f(vv.u[e]);
        __syncthreads();
#pragma unroll
        for (int jj = 0; jj < 32; ++jj) {
            float p0 = Ps[ty*2+0][jj];
            float p1 = Ps[ty*2+1][jj];
            float4 v4 = *(const float4*)&Vs[jj][tx*4];
            acc[0][0] += p0*v4.x; acc[0][1] += p0*v4.y; acc[0][2] += p0*v4.z; acc[0][3] += p0*v4.w;
            acc[1][0] += p1*v4.x; acc[1][1] += p1*v4.y; acc[1][2] += p1*v4.z; acc[1][3] += p1*v4.w;
        }
    }
#pragma unroll
    for (int a = 0; a < 2; ++a) {
        float4 o; o.x = acc[a][0]; o.y = acc[a][1]; o.z = acc[a][2]; o.w = acc[a][3];
        *(float4*)(rout + ((size_t)(s * L_DIM + i0 + ty*2 + a)) * D_DIM + h*64 + tx*4) = o;
    }
}

// ---------------------------------------------------------------------------
// out1_h = f16(LN(x + r)); x,r f32. grid NROW, block 256.
// ---------------------------------------------------------------------------
__global__ __launch_bounds__(256)
void add_ln_out16(const float* __restrict__ x, const float* __restrict__ r,
                  const float* __restrict__ g, const float* __restrict__ beta,
                  f16* __restrict__ out16)
{
    __shared__ float red[256];
    const int n = blockIdx.x, t = threadIdx.x;
    const float* xp = x + (size_t)n * D_DIM;
    const float* rp = r + (size_t)n * D_DIM;
    float v[3]; float s = 0.f;
#pragma unroll
    for (int e = 0; e < 3; ++e) { v[e] = xp[t + e*256] + rp[t + e*256]; s += v[e]; }
    red[t] = s; __syncthreads();
    for (int w = 128; w > 0; w >>= 1) { if (t < w) red[t] += red[t+w]; __syncthreads(); }
    float mean = red[0] * (1.f/768.f);
    __syncthreads();
    float sq = 0.f;
#pragma unroll
    for (int e = 0; e < 3; ++e) { float d = v[e] - mean; sq += d*d; }
    red[t] = sq; __syncthreads();
    for (int w = 128; w > 0; w >>= 1) { if (t < w) red[t] += red[t+w]; __syncthreads(); }
    float rstd = rsqrtf(red[0] * (1.f/768.f) + LN_EPS);
#pragma unroll
    for (int e = 0; e < 3; ++e) {
        int idx = t + e*256;
        out16[(size_t)n * D_DIM + idx] = (f16)((v[e] - mean) * rstd * g[idx] + beta[idx]);
    }
}

// ---------------------------------------------------------------------------
// out = LN(x16 + r) f32, in place on r. grid NROW, block 256.
// (all reads of r precede writes via the reduction barriers)
// ---------------------------------------------------------------------------
__global__ __launch_bounds__(256)
void add_ln_in16(const f16* __restrict__ x16, float* __restrict__ r,
                 const float* __restrict__ g, const float* __restrict__ beta)
{
    __shared__ float red[256];
    const int n = blockIdx.x, t = threadIdx.x;
    const f16*   xp = x16 + (size_t)n * D_DIM;
    float*       rp = r   + (size_t)n * D_DIM;
    float v[3]; float s = 0.f;
#pragma unroll
    for (int e = 0; e < 3; ++e) { v[e] = (float)xp[t + e*256] + rp[t + e*256]; s += v[e]; }
    red[t] = s; __syncthreads();
    for (int w = 128; w > 0; w >>= 1) { if (t < w) red[t] += red[t+w]; __syncthreads(); }
    float mean = red[0] * (1.f/768.f);
    __syncthreads();
    float sq = 0.f;
#pragma unroll
    for (int e = 0; e < 3; ++e) { float d = v[e] - mean; sq += d*d; }
    red[t] = sq; __syncthreads();
    for (int w = 128; w > 0; w >>= 1) { if (t < w) red[t] += red[t+w]; __syncthreads(); }
    float rstd = rsqrtf(red[0] * (1.f/768.f) + LN_EPS);
#pragma unroll
    for (int e = 0; e < 3; ++e) {
        int idx = t + e*256;
        rp[idx] = (v[e] - mean) * rstd * g[idx] + beta[idx];
    }
}

// ---------------------------------------------------------------------------
// Fused column attention for one (l, h, i-half); unchanged from round 2.
// grid (L, H, S/64); 256 threads. LDS 58.9 KB.
// ---------------------------------------------------------------------------
__global__ __launch_bounds__(256)
void col_attn(const u16* __restrict__ p, float* __restrict__ cout)
{
    __shared__ float smem_f[14976];                 // 59,904 B
    u16* Qs = (u16*)smem_f;                         // [64][68]  c-major
    u16* Ks = (u16*)((char*)smem_f + 8704);         // [64][132] c-major
    u16* Vs = (u16*)smem_f;                         // overlay [128][68]
    float* P = smem_f + 6400;                       // [128][67] P[j*67+i]

    const int tid = threadIdx.x;
    const int l = blockIdx.x, h = blockIdx.y;
    const int i0g = blockIdx.z * 64;

    {
        int qi = tid >> 2, qc = (tid & 3) * 16;
        const u16* qp = p + ((size_t)((i0g + qi) * L_DIM + l)) * TD + h*64 + qc;
        union { float4 f; u16 u[8]; } b0, b1;
        b0.f = *(const float4*)qp; b1.f = *(const float4*)(qp + 8);
#pragma unroll
        for (int e = 0; e < 8; ++e) {
            Qs[(qc+e)*68 + qi]   = b0.u[e];
            Qs[(qc+8+e)*68 + qi] = b1.u[e];
        }
        int kj = tid >> 1, kc = (tid & 1) * 32;
        const u16* kp = p + ((size_t)(kj * L_DIM + l)) * TD + 768 + h*64 + kc;
#pragma unroll
        for (int qq = 0; qq < 4; ++qq) {
            union { float4 f; u16 u[8]; } kb;
            kb.f = *(const float4*)(kp + qq*8);
#pragma unroll
            for (int e = 0; e < 8; ++e) Ks[(kc + qq*8 + e)*132 + kj] = kb.u[e];
        }
    }
    __syncthreads();

    {
        const int tx = tid & 15, ty = tid >> 4;
        const int jb = tx * 8, ib = ty * 4;
        float acc[4][8];
#pragma unroll
        for (int a = 0; a < 4; ++a)
#pragma unroll
            for (int b = 0; b < 8; ++b) acc[a][b] = 0.f;
        for (int c = 0; c < 64; ++c) {
            ushort4 qr = *(const ushort4*)&Qs[c*68 + ib];
            float qf[4] = {h2f(qr.x), h2f(qr.y), h2f(qr.z), h2f(qr.w)};
            union { float4 f; u16 u[8]; } kr;
            kr.f = *(const float4*)&Ks[c*132 + jb];
            float kf[8];
#pragma unroll
            for (int b = 0; b < 8; ++b) kf[b] = h2f(kr.u[b]);
#pragma unroll
            for (int a = 0; a < 4; ++a)
#pragma unroll
                for (int b = 0; b < 8; ++b)
                    acc[a][b] += qf[a] * kf[b];
        }
#pragma unroll
        for (int a = 0; a < 4; ++a)
#pragma unroll
            for (int b = 0; b < 8; ++b)
                P[(jb + b)*67 + ib + a] = acc[a][b];
    }
    __syncthreads();

    {
        int vj = tid >> 1, vd = (tid & 1) * 32;
        const u16* vp = p + ((size_t)(vj * L_DIM + l)) * TD + 1536 + h*64 + vd;
#pragma unroll
        for (int qq = 0; qq < 4; ++qq) {
            union { float4 f; ushort4 h2v[2]; } vb;
            vb.f = *(const float4*)(vp + qq*8);
            *(ushort4*)&Vs[vj*68 + vd + qq*8]     = vb.h2v[0];
            *(ushort4*)&Vs[vj*68 + vd + qq*8 + 4] = vb.h2v[1];
        }
    }
    __syncthreads();

    if (tid < 64) {
        float m = -1e30f;
        for (int j = 0; j < 128; ++j) m = fmaxf(m, P[j*67 + tid]);
        float sum = 0.f;
        for (int j = 0; j < 128; ++j) {
            float e = __expf(P[j*67 + tid] - m);
            P[j*67 + tid] = e; sum += e;
        }
        float inv = 1.f / sum;
        for (int j = 0; j < 128; ++j) P[j*67 + tid] *= inv;
    }
    __syncthreads();

    {
        int i = tid >> 2, dq = (tid & 3) * 16;
        float acc[16];
#pragma unroll
        for (int qq = 0; qq < 16; ++qq) acc[qq] = 0.f;
        for (int j = 0; j < 128; ++j) {
            float pw = P[j*67 + i];
#pragma unroll
            for (int qq = 0; qq < 4; ++qq) {
                ushort4 v4 = *(const ushort4*)&Vs[j*68 + dq + qq*4];
                acc[qq*4+0] += pw * h2f(v4.x);
                acc[qq*4+1] += pw * h2f(v4.y);
                acc[qq*4+2] += pw * h2f(v4.z);
                acc[qq*4+3] += pw * h2f(v4.w);
            }
        }
        float* op = cout + ((size_t)((i0g + i) * L_DIM + l)) * D_DIM + h*64 + dq;
#pragma unroll
        for (int qq = 0; qq < 4; ++qq) {
            float4 o; o.x = acc[qq*4+0]; o.y = acc[qq*4+1]; o.z = acc[qq*4+2]; o.w = acc[qq*4+3];
            *(float4*)(op + qq*4) = o;
        }
    }
}

// ---------------------------------------------------------------------------
extern "C" void kernel_launch(void* const* d_in, const int* in_sizes, int n_in,
                              void* d_out, int out_size, void* d_ws, size_t ws_size,
                              hipStream_t stream)
{
    const float* x     = (const float*)d_in[0];
    const float* w_row = (const float*)d_in[1];
    const float* b_row = (const float*)d_in[2];
    const float* w_col = (const float*)d_in[3];
    const float* b_col = (const float*)d_in[4];
    const float* g1    = (const float*)d_in[5];
    const float* be1   = (const float*)d_in[6];
    const float* g2    = (const float*)d_in[7];
    const float* be2   = (const float*)d_in[8];
    float* out = (float*)d_out;

    char* ws = (char*)d_ws;
    f16*   p      = (f16*)(ws + WS_P_OFF);
    float* logits = (float*)(ws + WS_LOGITS_OFF);
    f16*   xh     = (f16*)(ws + WS_XH_OFF);     // also out1_h after step 5
    f16*   wrh    = (f16*)(ws + WS_WRH_OFF);
    f16*   wch    = (f16*)(ws + WS_WCH_OFF);

    // 0) f32 -> f16 converts (x: 25.17M, w: 1.77M each)
    cvt_f32_f16<<<NROW * D_DIM / 1024, 256, 0, stream>>>(x, xh);
    cvt_f32_f16<<<TD * D_DIM / 1024, 256, 0, stream>>>(w_row, wrh);
    cvt_f32_f16<<<TD * D_DIM / 1024, 256, 0, stream>>>(w_col, wch);
    // 1) row QKV projection (MFMA) -> p (f16)
    mfma_gemm_qkv<<<dim3(TD/128, NROW/128), 256, 0, stream>>>(xh, wrh, b_row, p);
    // 2) tied row logits
    row_logits<<<dim3(L_DIM/32, L_DIM/32, H_DIM), 256, 0, stream>>>((const u16*)p, logits);
    // 3) softmax over j
    softmax256<<<H_DIM * L_DIM, 256, 0, stream>>>(logits);
    // 4) row PV -> d_out (scratch)
    row_pv<<<dim3(L_DIM/32, H_DIM, S_DIM), 256, 0, stream>>>(logits, (const u16*)p, out);
    // 5) out1_h = f16(LN(x + row_out))  (xh region is dead; reuse as out1_h)
    add_ln_out16<<<NROW, 256, 0, stream>>>(x, out, g1, be1, xh);
    // 6) col QKV projection (MFMA) -> p (f16)
    mfma_gemm_qkv<<<dim3(TD/128, NROW/128), 256, 0, stream>>>(xh, wch, b_col, p);
    // 7) fused column attention -> d_out (scratch)
    col_attn<<<dim3(L_DIM, H_DIM, S_DIM/64), 256, 0, stream>>>((const u16*)p, out);
    // 8) out = LN(out1_h + col_out), in place on d_out
    add_ln_in16<<<NROW, 256, 0, stream>>>(xh, out, g2, be2);
}

// Round 4
// 1190.706 us; speedup vs baseline: 3.2292x; 1.3541x over previous
//
#include <hip/hip_runtime.h>

// Problem constants (fixed by the reference): B=1
#define S_DIM 128
#define L_DIM 256
#define D_DIM 768
#define H_DIM 12
#define TD    2304            // 3*D
#define NROW  32768           // S*L
#define KDIM  768
#define LN_EPS 1e-5f

typedef unsigned short u16;
typedef unsigned int   u32;
typedef _Float16 f16;
typedef _Float16 f16x8 __attribute__((ext_vector_type(8)));
typedef _Float16 f16x4 __attribute__((ext_vector_type(4)));
typedef float    f32x4 __attribute__((ext_vector_type(4)));

// Workspace layout (bytes), total 224,133,120 (< 255 MB proven in rounds 1/2):
//  region R (151 MB, off 0) is time-multiplexed:
//    row phase : qt f16[H][L][8192] 50.33M | kt same | vbuf f16[NROW][768] 50.33M
//    col phase : p  f16[NROW][TD]  151 MB   (GEMM2 overwrites; qt/kt/vbuf dead)
//  lpart  : f32 [4][H][L][L]  12,582,912   (split-K partials for row logits)
//  logits : f32 [H][L][L]      3,145,728
//  xh/u1h : f16 [NROW][D]     50,331,648
//  wr_h   : f16 [TD][D]        3,538,944
//  wc_h   : f16 [TD][D]        3,538,944
#define WS_QT_OFF     0
#define WS_KT_OFF     50331648
#define WS_VB_OFF     100663296
#define WS_P_OFF      0
#define WS_LPART_OFF  150994944
#define WS_LOGITS_OFF 163577856
#define WS_XH_OFF     166723584
#define WS_WRH_OFF    217055232
#define WS_WCH_OFF    220594176

// fp16 staging (NOT bf16): row logits accumulate K=8192 products; bf16's
// 2^-9 rel-err gave final absmax 0.15 > 0.113 thr (round 1). fp16 passes
// at 0.047 (round 3) with fp16-input MFMA, fp32 accum.
__device__ __forceinline__ float h2f(u16 v) {
    union { u16 u; f16 h; } c; c.u = v; return (float)c.h;
}

__device__ __forceinline__ void gload_lds16(const void* g, void* l) {
    __builtin_amdgcn_global_load_lds((const __attribute__((address_space(1))) void*)g,
                                     (__attribute__((address_space(3))) void*)l, 16, 0, 0);
}

// ---------------------------------------------------------------------------
// f32 -> f16 convert, 4 elems/thread, grid sized exactly (n % 1024 == 0).
// ---------------------------------------------------------------------------
__global__ __launch_bounds__(256)
void cvt_f32_f16(const float* __restrict__ in, f16* __restrict__ out)
{
    int i = blockIdx.x * 256 + threadIdx.x;
    float4 v = ((const float4*)in)[i];
    f16x4 o; o.x = (f16)v.x; o.y = (f16)v.y; o.z = (f16)v.z; o.w = (f16)v.w;
    ((f16x4*)out)[i] = o;
}

// ---------------------------------------------------------------------------
// MFMA GEMM core (m97 pattern): 128x128 tile, BK=32, 256 thr = 4 waves (2x2
// of 64x64), each wave 4x4 of mfma_f32_16x16x32_f16. global_load_lds w=16;
// XOR chunk swizzle j ^= (m>>1)&3 keeps frag ds_read_b128 2-way (free, m136).
// Two epilogue variants below.
// ---------------------------------------------------------------------------
#define MFMA_PROLOG(KROW)                                                     \
    __shared__ f16 As[128 * 32];                                              \
    __shared__ f16 Bs[128 * 32];                                              \
    const int tid  = threadIdx.x;                                             \
    const int lane = tid & 63;                                                \
    const int w    = tid >> 6;                                                \
    const int wr   = (w >> 1) * 64;                                           \
    const int wc   = (w & 1) * 64;                                            \
    const int lm   = lane & 15;                                               \
    const int q    = lane >> 4;                                               \
    size_t soff[2];                                                           \
    int    ldsc[2];                                                           \
    _Pragma("unroll")                                                         \
    for (int t = 0; t < 2; ++t) {                                             \
        int c  = w * 128 + t * 64 + lane;                                     \
        int m  = c >> 2;                                                      \
        int gj = (c & 3) ^ ((m >> 1) & 3);                                    \
        soff[t] = (size_t)m * (KROW) + gj * 8;                                \
        ldsc[t] = (w * 128 + t * 64) * 8;                                     \
    }                                                                         \
    int chA[4], chB[4];                                                       \
    _Pragma("unroll")                                                         \
    for (int t = 0; t < 4; ++t) {                                             \
        int ma = wr + t * 16 + lm;                                            \
        chA[t] = ma * 4 + (q ^ ((ma >> 1) & 3));                              \
        int mb = wc + t * 16 + lm;                                            \
        chB[t] = mb * 4 + (q ^ ((mb >> 1) & 3));                              \
    }                                                                         \
    f32x4 acc[4][4];                                                          \
    _Pragma("unroll")                                                         \
    for (int i = 0; i < 4; ++i)                                               \
        _Pragma("unroll")                                                     \
        for (int j = 0; j < 4; ++j) acc[i][j] = (f32x4)0.f;

#define MFMA_KLOOP(baseA, baseB, KLEN)                                        \
    for (int k0 = 0; k0 < (KLEN); k0 += 32) {                                 \
        _Pragma("unroll")                                                     \
        for (int t = 0; t < 2; ++t) {                                         \
            gload_lds16((baseA) + soff[t] + k0, &As[ldsc[t]]);                \
            gload_lds16((baseB) + soff[t] + k0, &Bs[ldsc[t]]);                \
        }                                                                     \
        __syncthreads();                                                      \
        f16x8 af[4], bf[4];                                                   \
        _Pragma("unroll")                                                     \
        for (int t = 0; t < 4; ++t) af[t] = *(const f16x8*)&As[chA[t] * 8];   \
        _Pragma("unroll")                                                     \
        for (int t = 0; t < 4; ++t) bf[t] = *(const f16x8*)&Bs[chB[t] * 8];   \
        _Pragma("unroll")                                                     \
        for (int mt = 0; mt < 4; ++mt)                                        \
            _Pragma("unroll")                                                 \
            for (int nt = 0; nt < 4; ++nt)                                    \
                acc[mt][nt] = __builtin_amdgcn_mfma_f32_16x16x32_f16(         \
                    af[mt], bf[nt], acc[mt][nt], 0, 0, 0);                    \
        __syncthreads();                                                      \
    }

// ---------------------------------------------------------------------------
// GEMM2 (col QKV): C = A*W^T + bias -> p f16 [NROW][TD]. grid (18, 256).
// ---------------------------------------------------------------------------
__global__ __launch_bounds__(256)
void mfma_gemm_qkv(const f16* __restrict__ A, const f16* __restrict__ W,
                   const float* __restrict__ bias, f16* __restrict__ C)
{
    const int row0 = blockIdx.y * 128;
    const int col0 = blockIdx.x * 128;
    MFMA_PROLOG(KDIM)
    const f16* baseA = A + (size_t)row0 * KDIM;
    const f16* baseB = W + (size_t)col0 * KDIM;
    MFMA_KLOOP(baseA, baseB, KDIM)

    // C/D layout: col=lane&15, row=quad*4+reg
    float bv[4];
#pragma unroll
    for (int nt = 0; nt < 4; ++nt) bv[nt] = bias[col0 + wc + nt * 16 + lm];
#pragma unroll
    for (int mt = 0; mt < 4; ++mt) {
        int grow = row0 + wr + mt * 16 + q * 4;
#pragma unroll
        for (int nt = 0; nt < 4; ++nt) {
            int gcol = col0 + wc + nt * 16 + lm;
#pragma unroll
            for (int r = 0; r < 4; ++r)
                C[(size_t)(grow + r) * TD + gcol] = (f16)(acc[mt][nt][r] + bv[nt]);
        }
    }
}

// ---------------------------------------------------------------------------
// GEMM1 (row QKV): same GEMM but scatter epilogue:
//   q -> qt[h][i][s*64+c]  (K-major for the logits GEMM)
//   k -> kt[h][j][s*64+c]
//   v -> vbuf[n][768]
// col0 is a multiple of 128 and region boundaries are at 768/1536 -> the
// region branch is block-uniform. n = s*256+i; a 128-row tile has fixed s.
// ---------------------------------------------------------------------------
__global__ __launch_bounds__(256)
void mfma_gemm_row(const f16* __restrict__ A, const f16* __restrict__ W,
                   const float* __restrict__ bias,
                   f16* __restrict__ qt, f16* __restrict__ kt,
                   f16* __restrict__ vbuf)
{
    const int row0 = blockIdx.y * 128;
    const int col0 = blockIdx.x * 128;
    MFMA_PROLOG(KDIM)
    const f16* baseA = A + (size_t)row0 * KDIM;
    const f16* baseB = W + (size_t)col0 * KDIM;
    MFMA_KLOOP(baseA, baseB, KDIM)

    if (col0 < 1536) {
        f16* dst = (col0 < 768) ? qt : kt;
        const int cbase = (col0 < 768) ? col0 : col0 - 768;
#pragma unroll
        for (int nt = 0; nt < 4; ++nt) {
            int gcol = cbase + wc + nt * 16 + lm;
            int h = gcol >> 6, c = gcol & 63;
            float b = bias[col0 + wc + nt * 16 + lm];
#pragma unroll
            for (int mt = 0; mt < 4; ++mt) {
                int n0 = row0 + wr + mt * 16 + q * 4;
#pragma unroll
                for (int r = 0; r < 4; ++r) {
                    int n = n0 + r;
                    int s = n >> 8, i = n & 255;
                    dst[(((size_t)h * 256 + i) * 128 + s) * 64 + c] =
                        (f16)(acc[mt][nt][r] + b);
                }
            }
        }
    } else {
#pragma unroll
        for (int nt = 0; nt < 4; ++nt) {
            int gcol = col0 + wc + nt * 16 + lm;
            float b = bias[gcol];
#pragma unroll
            for (int mt = 0; mt < 4; ++mt) {
                int n0 = row0 + wr + mt * 16 + q * 4;
#pragma unroll
                for (int r = 0; r < 4; ++r)
                    vbuf[(size_t)(n0 + r) * 768 + (gcol - 1536)] =
                        (f16)(acc[mt][nt][r] + b);
            }
        }
    }
}

// ---------------------------------------------------------------------------
// Row logits via MFMA: lpart[sp][h][i][j] = sum_{k in split sp} qt[h][i][k]*
// kt[h][j][k], K=8192 split 4 ways. grid (2, 2, 48): z = h*4+sp.
// ---------------------------------------------------------------------------
__global__ __launch_bounds__(256)
void row_logits_mfma(const f16* __restrict__ qt, const f16* __restrict__ kt,
                     float* __restrict__ lpart)
{
    const int i0 = blockIdx.y * 128;
    const int j0 = blockIdx.x * 128;
    const int h  = blockIdx.z >> 2;
    const int sp = blockIdx.z & 3;
    MFMA_PROLOG(8192)
    const f16* baseA = qt + ((size_t)h * 256 + i0) * 8192 + sp * 2048;
    const f16* baseB = kt + ((size_t)h * 256 + j0) * 8192 + sp * 2048;
    MFMA_KLOOP(baseA, baseB, 2048)

    float* outp = lpart + (size_t)(sp * 12 + h) * 65536;
#pragma unroll
    for (int mt = 0; mt < 4; ++mt) {
        int grow = i0 + wr + mt * 16 + q * 4;
#pragma unroll
        for (int nt = 0; nt < 4; ++nt) {
            int gcol = j0 + wc + nt * 16 + lm;
#pragma unroll
            for (int r = 0; r < 4; ++r)
                outp[(size_t)(grow + r) * 256 + gcol] = acc[mt][nt][r];
        }
    }
}

// ---------------------------------------------------------------------------
// softmax over rows of 256, summing 4 split-K partials. grid = H*L, block 256.
// ---------------------------------------------------------------------------
__global__ __launch_bounds__(256)
void softmax256_4(const float* __restrict__ lpart, float* __restrict__ logits)
{
    __shared__ float red[256];
    const int t = threadIdx.x;
    const size_t idx = (size_t)blockIdx.x * 256 + t;
    const size_t P = (size_t)12 * 65536;
    float v = lpart[idx] + lpart[idx + P] + lpart[idx + 2*P] + lpart[idx + 3*P];
    red[t] = v; __syncthreads();
    for (int w = 128; w > 0; w >>= 1) { if (t < w) red[t] = fmaxf(red[t], red[t+w]); __syncthreads(); }
    float m = red[0];
    __syncthreads();
    float e = __expf(v - m);
    red[t] = e; __syncthreads();
    for (int w = 128; w > 0; w >>= 1) { if (t < w) red[t] += red[t+w]; __syncthreads(); }
    logits[idx] = e / red[0];
}

// ---------------------------------------------------------------------------
// rout[(s*L+i)*D + h*64 + d] = sum_j attn[h][i][j] * v[s,j,h,d]; v from vbuf.
// grid (L/32, H, S); 256 threads; 2(i) x 4(d) micro-tile; K-tile 32 over j.
// ---------------------------------------------------------------------------
__global__ __launch_bounds__(256)
void row_pv(const float* __restrict__ attn, const f16* __restrict__ vbuf,
            float* __restrict__ rout)
{
    __shared__ float Ps[32][33];
    __shared__ float Vs[32][68];
    const int tid = threadIdx.x;
    const int tx = tid & 15, ty = tid >> 4;
    const int i0 = blockIdx.x * 32;
    const int h  = blockIdx.y;
    const int s  = blockIdx.z;
    const float* arow = attn + ((size_t)h * L_DIM + i0) * L_DIM;
    const int pr = tid >> 3, pc = (tid & 7) * 4;
    const int vr = tid >> 3, vc = (tid & 7) * 8;
    float acc[2][4] = {{0.f,0.f,0.f,0.f},{0.f,0.f,0.f,0.f}};

    for (int j0 = 0; j0 < L_DIM; j0 += 32) {
        float4 pv = *(const float4*)(arow + (size_t)pr * L_DIM + j0 + pc);
        union { float4 f; u16 u[8]; } vv;
        vv.f = *(const float4*)(vbuf + (size_t)(s * L_DIM + j0 + vr) * 768 + h*64 + vc);
        __syncthreads();
        Ps[pr][pc+0] = pv.x; Ps[pr][pc+1] = pv.y; Ps[pr][pc+2] = pv.z; Ps[pr][pc+3] = pv.w;
#pragma unroll
        for (int e = 0; e < 8; ++e) Vs[vr][vc+e] = h2f(vv.u[e]);
        __syncthreads();
#pragma unroll
        for (int jj = 0; jj < 32; ++jj) {
            float p0 = Ps[ty*2+0][jj];
            float p1 = Ps[ty*2+1][jj];
            float4 v4 = *(const float4*)&Vs[jj][tx*4];
            acc[0][0] += p0*v4.x; acc[0][1] += p0*v4.y; acc[0][2] += p0*v4.z; acc[0][3] += p0*v4.w;
            acc[1][0] += p1*v4.x; acc[1][1] += p1*v4.y; acc[1][2] += p1*v4.z; acc[1][3] += p1*v4.w;
        }
    }
#pragma unroll
    for (int a = 0; a < 2; ++a) {
        float4 o; o.x = acc[a][0]; o.y = acc[a][1]; o.z = acc[a][2]; o.w = acc[a][3];
        *(float4*)(rout + ((size_t)(s * L_DIM + i0 + ty*2 + a)) * D_DIM + h*64 + tx*4) = o;
    }
}

// ---------------------------------------------------------------------------
// out1_h = f16(LN(x + r)); x,r f32. grid NROW, block 256.
// ---------------------------------------------------------------------------
__global__ __launch_bounds__(256)
void add_ln_out16(const float* __restrict__ x, const float* __restrict__ r,
                  const float* __restrict__ g, const float* __restrict__ beta,
                  f16* __restrict__ out16)
{
    __shared__ float red[256];
    const int n = blockIdx.x, t = threadIdx.x;
    const float* xp = x + (size_t)n * D_DIM;
    const float* rp = r + (size_t)n * D_DIM;
    float v[3]; float s = 0.f;
#pragma unroll
    for (int e = 0; e < 3; ++e) { v[e] = xp[t + e*256] + rp[t + e*256]; s += v[e]; }
    red[t] = s; __syncthreads();
    for (int w = 128; w > 0; w >>= 1) { if (t < w) red[t] += red[t+w]; __syncthreads(); }
    float mean = red[0] * (1.f/768.f);
    __syncthreads();
    float sq = 0.f;
#pragma unroll
    for (int e = 0; e < 3; ++e) { float d = v[e] - mean; sq += d*d; }
    red[t] = sq; __syncthreads();
    for (int w = 128; w > 0; w >>= 1) { if (t < w) red[t] += red[t+w]; __syncthreads(); }
    float rstd = rsqrtf(red[0] * (1.f/768.f) + LN_EPS);
#pragma unroll
    for (int e = 0; e < 3; ++e) {
        int idx = t + e*256;
        out16[(size_t)n * D_DIM + idx] = (f16)((v[e] - mean) * rstd * g[idx] + beta[idx]);
    }
}

// ---------------------------------------------------------------------------
// out = LN(x16 + r) f32, in place on r. grid NROW, block 256.
// ---------------------------------------------------------------------------
__global__ __launch_bounds__(256)
void add_ln_in16(const f16* __restrict__ x16, float* __restrict__ r,
                 const float* __restrict__ g, const float* __restrict__ beta)
{
    __shared__ float red[256];
    const int n = blockIdx.x, t = threadIdx.x;
    const f16*   xp = x16 + (size_t)n * D_DIM;
    float*       rp = r   + (size_t)n * D_DIM;
    float v[3]; float s = 0.f;
#pragma unroll
    for (int e = 0; e < 3; ++e) { v[e] = (float)xp[t + e*256] + rp[t + e*256]; s += v[e]; }
    red[t] = s; __syncthreads();
    for (int w = 128; w > 0; w >>= 1) { if (t < w) red[t] += red[t+w]; __syncthreads(); }
    float mean = red[0] * (1.f/768.f);
    __syncthreads();
    float sq = 0.f;
#pragma unroll
    for (int e = 0; e < 3; ++e) { float d = v[e] - mean; sq += d*d; }
    red[t] = sq; __syncthreads();
    for (int w = 128; w > 0; w >>= 1) { if (t < w) red[t] += red[t+w]; __syncthreads(); }
    float rstd = rsqrtf(red[0] * (1.f/768.f) + LN_EPS);
#pragma unroll
    for (int e = 0; e < 3; ++e) {
        int idx = t + e*256;
        rp[idx] = (v[e] - mean) * rstd * g[idx] + beta[idx];
    }
}

// ---------------------------------------------------------------------------
// Fused column attention for one (l, h, i-half); unchanged from round 3.
// grid (L, H, S/64); 256 threads. LDS 58.9 KB.
// ---------------------------------------------------------------------------
__global__ __launch_bounds__(256)
void col_attn(const u16* __restrict__ p, float* __restrict__ cout)
{
    __shared__ float smem_f[14976];                 // 59,904 B
    u16* Qs = (u16*)smem_f;                         // [64][68]  c-major
    u16* Ks = (u16*)((char*)smem_f + 8704);         // [64][132] c-major
    u16* Vs = (u16*)smem_f;                         // overlay [128][68]
    float* P = smem_f + 6400;                       // [128][67] P[j*67+i]

    const int tid = threadIdx.x;
    const int l = blockIdx.x, h = blockIdx.y;
    const int i0g = blockIdx.z * 64;

    {
        int qi = tid >> 2, qc = (tid & 3) * 16;
        const u16* qp = p + ((size_t)((i0g + qi) * L_DIM + l)) * TD + h*64 + qc;
        union { float4 f; u16 u[8]; } b0, b1;
        b0.f = *(const float4*)qp; b1.f = *(const float4*)(qp + 8);
#pragma unroll
        for (int e = 0; e < 8; ++e) {
            Qs[(qc+e)*68 + qi]   = b0.u[e];
            Qs[(qc+8+e)*68 + qi] = b1.u[e];
        }
        int kj = tid >> 1, kc = (tid & 1) * 32;
        const u16* kp = p + ((size_t)(kj * L_DIM + l)) * TD + 768 + h*64 + kc;
#pragma unroll
        for (int qq = 0; qq < 4; ++qq) {
            union { float4 f; u16 u[8]; } kb;
            kb.f = *(const float4*)(kp + qq*8);
#pragma unroll
            for (int e = 0; e < 8; ++e) Ks[(kc + qq*8 + e)*132 + kj] = kb.u[e];
        }
    }
    __syncthreads();

    {
        const int tx = tid & 15, ty = tid >> 4;
        const int jb = tx * 8, ib = ty * 4;
        float acc[4][8];
#pragma unroll
        for (int a = 0; a < 4; ++a)
#pragma unroll
            for (int b = 0; b < 8; ++b) acc[a][b] = 0.f;
        for (int c = 0; c < 64; ++c) {
            ushort4 qr = *(const ushort4*)&Qs[c*68 + ib];
            float qf[4] = {h2f(qr.x), h2f(qr.y), h2f(qr.z), h2f(qr.w)};
            union { float4 f; u16 u[8]; } kr;
            kr.f = *(const float4*)&Ks[c*132 + jb];
            float kf[8];
#pragma unroll
            for (int b = 0; b < 8; ++b) kf[b] = h2f(kr.u[b]);
#pragma unroll
            for (int a = 0; a < 4; ++a)
#pragma unroll
                for (int b = 0; b < 8; ++b)
                    acc[a][b] += qf[a] * kf[b];
        }
#pragma unroll
        for (int a = 0; a < 4; ++a)
#pragma unroll
            for (int b = 0; b < 8; ++b)
                P[(jb + b)*67 + ib + a] = acc[a][b];
    }
    __syncthreads();

    {
        int vj = tid >> 1, vd = (tid & 1) * 32;
        const u16* vp = p + ((size_t)(vj * L_DIM + l)) * TD + 1536 + h*64 + vd;
#pragma unroll
        for (int qq = 0; qq < 4; ++qq) {
            union { float4 f; ushort4 h2v[2]; } vb;
            vb.f = *(const float4*)(vp + qq*8);
            *(ushort4*)&Vs[vj*68 + vd + qq*8]     = vb.h2v[0];
            *(ushort4*)&Vs[vj*68 + vd + qq*8 + 4] = vb.h2v[1];
        }
    }
    __syncthreads();

    if (tid < 64) {
        float m = -1e30f;
        for (int j = 0; j < 128; ++j) m = fmaxf(m, P[j*67 + tid]);
        float sum = 0.f;
        for (int j = 0; j < 128; ++j) {
            float e = __expf(P[j*67 + tid] - m);
            P[j*67 + tid] = e; sum += e;
        }
        float inv = 1.f / sum;
        for (int j = 0; j < 128; ++j) P[j*67 + tid] *= inv;
    }
    __syncthreads();

    {
        int i = tid >> 2, dq = (tid & 3) * 16;
        float acc[16];
#pragma unroll
        for (int qq = 0; qq < 16; ++qq) acc[qq] = 0.f;
        for (int j = 0; j < 128; ++j) {
            float pw = P[j*67 + i];
#pragma unroll
            for (int qq = 0; qq < 4; ++qq) {
                ushort4 v4 = *(const ushort4*)&Vs[j*68 + dq + qq*4];
                acc[qq*4+0] += pw * h2f(v4.x);
                acc[qq*4+1] += pw * h2f(v4.y);
                acc[qq*4+2] += pw * h2f(v4.z);
                acc[qq*4+3] += pw * h2f(v4.w);
            }
        }
        float* op = cout + ((size_t)((i0g + i) * L_DIM + l)) * D_DIM + h*64 + dq;
#pragma unroll
        for (int qq = 0; qq < 4; ++qq) {
            float4 o; o.x = acc[qq*4+0]; o.y = acc[qq*4+1]; o.z = acc[qq*4+2]; o.w = acc[qq*4+3];
            *(float4*)(op + qq*4) = o;
        }
    }
}

// ---------------------------------------------------------------------------
extern "C" void kernel_launch(void* const* d_in, const int* in_sizes, int n_in,
                              void* d_out, int out_size, void* d_ws, size_t ws_size,
                              hipStream_t stream)
{
    const float* x     = (const float*)d_in[0];
    const float* w_row = (const float*)d_in[1];
    const float* b_row = (const float*)d_in[2];
    const float* w_col = (const float*)d_in[3];
    const float* b_col = (const float*)d_in[4];
    const float* g1    = (const float*)d_in[5];
    const float* be1   = (const float*)d_in[6];
    const float* g2    = (const float*)d_in[7];
    const float* be2   = (const float*)d_in[8];
    float* out = (float*)d_out;

    char* ws = (char*)d_ws;
    f16*   qt     = (f16*)(ws + WS_QT_OFF);
    f16*   kt     = (f16*)(ws + WS_KT_OFF);
    f16*   vbuf   = (f16*)(ws + WS_VB_OFF);
    f16*   p      = (f16*)(ws + WS_P_OFF);      // col phase, aliases qt/kt/vbuf
    float* lpart  = (float*)(ws + WS_LPART_OFF);
    float* logits = (float*)(ws + WS_LOGITS_OFF);
    f16*   xh     = (f16*)(ws + WS_XH_OFF);     // also out1_h after step 5
    f16*   wrh    = (f16*)(ws + WS_WRH_OFF);
    f16*   wch    = (f16*)(ws + WS_WCH_OFF);

    // 0) f32 -> f16 converts
    cvt_f32_f16<<<NROW * D_DIM / 1024, 256, 0, stream>>>(x, xh);
    cvt_f32_f16<<<TD * D_DIM / 1024, 256, 0, stream>>>(w_row, wrh);
    cvt_f32_f16<<<TD * D_DIM / 1024, 256, 0, stream>>>(w_col, wch);
    // 1) row QKV projection (MFMA) -> qt/kt (K-major) + vbuf
    mfma_gemm_row<<<dim3(TD/128, NROW/128), 256, 0, stream>>>(xh, wrh, b_row, qt, kt, vbuf);
    // 2) tied row logits (MFMA, split-K=4)
    row_logits_mfma<<<dim3(2, 2, 48), 256, 0, stream>>>(qt, kt, lpart);
    // 3) softmax over j (sums 4 partials)
    softmax256_4<<<H_DIM * L_DIM, 256, 0, stream>>>(lpart, logits);
    // 4) row PV -> d_out (scratch)
    row_pv<<<dim3(L_DIM/32, H_DIM, S_DIM), 256, 0, stream>>>(logits, vbuf, out);
    // 5) out1_h = f16(LN(x + row_out))  (xh dead; reuse as out1_h)
    add_ln_out16<<<NROW, 256, 0, stream>>>(x, out, g1, be1, xh);
    // 6) col QKV projection (MFMA) -> p (overwrites qt/kt/vbuf region)
    mfma_gemm_qkv<<<dim3(TD/128, NROW/128), 256, 0, stream>>>(xh, wch, b_col, p);
    // 7) fused column attention -> d_out (scratch)
    col_attn<<<dim3(L_DIM, H_DIM, S_DIM/64), 256, 0, stream>>>((const u16*)p, out);
    // 8) out = LN(out1_h + col_out), in place on d_out
    add_ln_in16<<<NROW, 256, 0, stream>>>(xh, out, g2, be2);
}

// Round 5
// 912.675 us; speedup vs baseline: 4.2129x; 1.3046x over previous
//
#include <hip/hip_runtime.h>

// Problem constants (fixed by the reference): B=1
#define S_DIM 128
#define L_DIM 256
#define D_DIM 768
#define H_DIM 12
#define TD    2304            // 3*D
#define NROW  32768           // S*L
#define KDIM  768
#define LN_EPS 1e-5f

typedef unsigned short u16;
typedef unsigned int   u32;
typedef _Float16 f16;
typedef _Float16 f16x8 __attribute__((ext_vector_type(8)));
typedef _Float16 f16x4 __attribute__((ext_vector_type(4)));
typedef float    f32x4 __attribute__((ext_vector_type(4)));

// Workspace layout (bytes), total 224,133,120 (< 255 MB proven in rounds 1/2):
//  region R (151 MB, off 0) is time-multiplexed:
//    row phase : qt f16[H][L][8192] 50.33M | kt same | vbuf f16[NROW][768] 50.33M
//    col phase : p  f16[NROW][TD]  151 MB   (GEMM2 overwrites; qt/kt/vbuf dead)
//  lpart  : f32 [4][H][L][L]  12,582,912   (split-K partials for row logits)
//  logits : f32 [H][L][L]      3,145,728
//  xh/u1h : f16 [NROW][D]     50,331,648
//  wr_h   : f16 [TD][D]        3,538,944
//  wc_h   : f16 [TD][D]        3,538,944
#define WS_QT_OFF     0
#define WS_KT_OFF     50331648
#define WS_VB_OFF     100663296
#define WS_P_OFF      0
#define WS_LPART_OFF  150994944
#define WS_LOGITS_OFF 163577856
#define WS_XH_OFF     166723584
#define WS_WRH_OFF    217055232
#define WS_WCH_OFF    220594176

// fp16 staging (NOT bf16): row logits accumulate K=8192 products; bf16's
// 2^-9 rel-err gave final absmax 0.15 > 0.113 thr (round 1). fp16 passes
// at 0.047 (rounds 3/4) with fp16-input MFMA, fp32 accum.
__device__ __forceinline__ float h2f(u16 v) {
    union { u16 u; f16 h; } c; c.u = v; return (float)c.h;
}

__device__ __forceinline__ void gload_lds16(const void* g, void* l) {
    __builtin_amdgcn_global_load_lds((const __attribute__((address_space(1))) void*)g,
                                     (__attribute__((address_space(3))) void*)l, 16, 0, 0);
}

// ---------------------------------------------------------------------------
// f32 -> f16 convert, 4 elems/thread, grid sized exactly (n % 1024 == 0).
// ---------------------------------------------------------------------------
__global__ __launch_bounds__(256)
void cvt_f32_f16(const float* __restrict__ in, f16* __restrict__ out)
{
    int i = blockIdx.x * 256 + threadIdx.x;
    float4 v = ((const float4*)in)[i];
    f16x4 o; o.x = (f16)v.x; o.y = (f16)v.y; o.z = (f16)v.z; o.w = (f16)v.w;
    ((f16x4*)out)[i] = o;
}

// ---------------------------------------------------------------------------
// MFMA GEMM core (m97 pattern): 128x128 tile, BK=32, 256 thr = 4 waves (2x2
// of 64x64), each wave 4x4 of mfma_f32_16x16x32_f16. global_load_lds w=16;
// XOR chunk swizzle j ^= (m>>1)&3 keeps frag ds_read_b128 2-way (free, m136).
// ---------------------------------------------------------------------------
#define MFMA_PROLOG(KROW)                                                     \
    __shared__ f16 As[128 * 32];                                              \
    __shared__ f16 Bs[128 * 32];                                              \
    const int tid  = threadIdx.x;                                             \
    const int lane = tid & 63;                                                \
    const int w    = tid >> 6;                                                \
    const int wr   = (w >> 1) * 64;                                           \
    const int wc   = (w & 1) * 64;                                            \
    const int lm   = lane & 15;                                               \
    const int q    = lane >> 4;                                               \
    size_t soff[2];                                                           \
    int    ldsc[2];                                                           \
    _Pragma("unroll")                                                         \
    for (int t = 0; t < 2; ++t) {                                             \
        int c  = w * 128 + t * 64 + lane;                                     \
        int m  = c >> 2;                                                      \
        int gj = (c & 3) ^ ((m >> 1) & 3);                                    \
        soff[t] = (size_t)m * (KROW) + gj * 8;                                \
        ldsc[t] = (w * 128 + t * 64) * 8;                                     \
    }                                                                         \
    int chA[4], chB[4];                                                       \
    _Pragma("unroll")                                                         \
    for (int t = 0; t < 4; ++t) {                                             \
        int ma = wr + t * 16 + lm;                                            \
        chA[t] = ma * 4 + (q ^ ((ma >> 1) & 3));                              \
        int mb = wc + t * 16 + lm;                                            \
        chB[t] = mb * 4 + (q ^ ((mb >> 1) & 3));                              \
    }                                                                         \
    f32x4 acc[4][4];                                                          \
    _Pragma("unroll")                                                         \
    for (int i = 0; i < 4; ++i)                                               \
        _Pragma("unroll")                                                     \
        for (int j = 0; j < 4; ++j) acc[i][j] = (f32x4)0.f;

#define MFMA_KLOOP(baseA, baseB, KLEN)                                        \
    for (int k0 = 0; k0 < (KLEN); k0 += 32) {                                 \
        _Pragma("unroll")                                                     \
        for (int t = 0; t < 2; ++t) {                                         \
            gload_lds16((baseA) + soff[t] + k0, &As[ldsc[t]]);                \
            gload_lds16((baseB) + soff[t] + k0, &Bs[ldsc[t]]);                \
        }                                                                     \
        __syncthreads();                                                      \
        f16x8 af[4], bf[4];                                                   \
        _Pragma("unroll")                                                     \
        for (int t = 0; t < 4; ++t) af[t] = *(const f16x8*)&As[chA[t] * 8];   \
        _Pragma("unroll")                                                     \
        for (int t = 0; t < 4; ++t) bf[t] = *(const f16x8*)&Bs[chB[t] * 8];   \
        _Pragma("unroll")                                                     \
        for (int mt = 0; mt < 4; ++mt)                                        \
            _Pragma("unroll")                                                 \
            for (int nt = 0; nt < 4; ++nt)                                    \
                acc[mt][nt] = __builtin_amdgcn_mfma_f32_16x16x32_f16(         \
                    af[mt], bf[nt], acc[mt][nt], 0, 0, 0);                    \
        __syncthreads();                                                      \
    }

// ---------------------------------------------------------------------------
// GEMM2 (col QKV): C = A*W^T + bias -> p f16 [NROW][TD]. grid (18, 256).
// ---------------------------------------------------------------------------
__global__ __launch_bounds__(256)
void mfma_gemm_qkv(const f16* __restrict__ A, const f16* __restrict__ W,
                   const float* __restrict__ bias, f16* __restrict__ C)
{
    const int row0 = blockIdx.y * 128;
    const int col0 = blockIdx.x * 128;
    MFMA_PROLOG(KDIM)
    const f16* baseA = A + (size_t)row0 * KDIM;
    const f16* baseB = W + (size_t)col0 * KDIM;
    MFMA_KLOOP(baseA, baseB, KDIM)

    // C/D layout: col=lane&15, row=quad*4+reg
    float bv[4];
#pragma unroll
    for (int nt = 0; nt < 4; ++nt) bv[nt] = bias[col0 + wc + nt * 16 + lm];
#pragma unroll
    for (int mt = 0; mt < 4; ++mt) {
        int grow = row0 + wr + mt * 16 + q * 4;
#pragma unroll
        for (int nt = 0; nt < 4; ++nt) {
            int gcol = col0 + wc + nt * 16 + lm;
#pragma unroll
            for (int r = 0; r < 4; ++r)
                C[(size_t)(grow + r) * TD + gcol] = (f16)(acc[mt][nt][r] + bv[nt]);
        }
    }
}

// ---------------------------------------------------------------------------
// GEMM1 (row QKV): same GEMM but scatter epilogue:
//   q -> qt[h][i][s*64+c], k -> kt[h][j][s*64+c], v -> vbuf[n][768]
// ---------------------------------------------------------------------------
__global__ __launch_bounds__(256)
void mfma_gemm_row(const f16* __restrict__ A, const f16* __restrict__ W,
                   const float* __restrict__ bias,
                   f16* __restrict__ qt, f16* __restrict__ kt,
                   f16* __restrict__ vbuf)
{
    const int row0 = blockIdx.y * 128;
    const int col0 = blockIdx.x * 128;
    MFMA_PROLOG(KDIM)
    const f16* baseA = A + (size_t)row0 * KDIM;
    const f16* baseB = W + (size_t)col0 * KDIM;
    MFMA_KLOOP(baseA, baseB, KDIM)

    if (col0 < 1536) {
        f16* dst = (col0 < 768) ? qt : kt;
        const int cbase = (col0 < 768) ? col0 : col0 - 768;
#pragma unroll
        for (int nt = 0; nt < 4; ++nt) {
            int gcol = cbase + wc + nt * 16 + lm;
            int h = gcol >> 6, c = gcol & 63;
            float b = bias[col0 + wc + nt * 16 + lm];
#pragma unroll
            for (int mt = 0; mt < 4; ++mt) {
                int n0 = row0 + wr + mt * 16 + q * 4;
#pragma unroll
                for (int r = 0; r < 4; ++r) {
                    int n = n0 + r;
                    int s = n >> 8, i = n & 255;
                    dst[(((size_t)h * 256 + i) * 128 + s) * 64 + c] =
                        (f16)(acc[mt][nt][r] + b);
                }
            }
        }
    } else {
#pragma unroll
        for (int nt = 0; nt < 4; ++nt) {
            int gcol = col0 + wc + nt * 16 + lm;
            float b = bias[gcol];
#pragma unroll
            for (int mt = 0; mt < 4; ++mt) {
                int n0 = row0 + wr + mt * 16 + q * 4;
#pragma unroll
                for (int r = 0; r < 4; ++r)
                    vbuf[(size_t)(n0 + r) * 768 + (gcol - 1536)] =
                        (f16)(acc[mt][nt][r] + b);
            }
        }
    }
}

// ---------------------------------------------------------------------------
// Row logits via MFMA: split-K=4 partials. grid (2, 2, 48): z = h*4+sp.
// ---------------------------------------------------------------------------
__global__ __launch_bounds__(256)
void row_logits_mfma(const f16* __restrict__ qt, const f16* __restrict__ kt,
                     float* __restrict__ lpart)
{
    const int i0 = blockIdx.y * 128;
    const int j0 = blockIdx.x * 128;
    const int h  = blockIdx.z >> 2;
    const int sp = blockIdx.z & 3;
    MFMA_PROLOG(8192)
    const f16* baseA = qt + ((size_t)h * 256 + i0) * 8192 + sp * 2048;
    const f16* baseB = kt + ((size_t)h * 256 + j0) * 8192 + sp * 2048;
    MFMA_KLOOP(baseA, baseB, 2048)

    float* outp = lpart + (size_t)(sp * 12 + h) * 65536;
#pragma unroll
    for (int mt = 0; mt < 4; ++mt) {
        int grow = i0 + wr + mt * 16 + q * 4;
#pragma unroll
        for (int nt = 0; nt < 4; ++nt) {
            int gcol = j0 + wc + nt * 16 + lm;
#pragma unroll
            for (int r = 0; r < 4; ++r)
                outp[(size_t)(grow + r) * 256 + gcol] = acc[mt][nt][r];
        }
    }
}

// ---------------------------------------------------------------------------
// softmax over rows of 256, summing 4 split-K partials. grid = H*L, block 256.
// ---------------------------------------------------------------------------
__global__ __launch_bounds__(256)
void softmax256_4(const float* __restrict__ lpart, float* __restrict__ logits)
{
    __shared__ float red[256];
    const int t = threadIdx.x;
    const size_t idx = (size_t)blockIdx.x * 256 + t;
    const size_t P = (size_t)12 * 65536;
    float v = lpart[idx] + lpart[idx + P] + lpart[idx + 2*P] + lpart[idx + 3*P];
    red[t] = v; __syncthreads();
    for (int w = 128; w > 0; w >>= 1) { if (t < w) red[t] = fmaxf(red[t], red[t+w]); __syncthreads(); }
    float m = red[0];
    __syncthreads();
    float e = __expf(v - m);
    red[t] = e; __syncthreads();
    for (int w = 128; w > 0; w >>= 1) { if (t < w) red[t] += red[t+w]; __syncthreads(); }
    logits[idx] = e / red[0];
}

// ---------------------------------------------------------------------------
// rout[(s*L+i)*D + h*64 + d] = sum_j attn[h][i][j] * v[s,j,h,d]; v from vbuf.
// grid (L/32, H, S); 256 threads; 2(i) x 4(d) micro-tile; K-tile 32 over j.
// ---------------------------------------------------------------------------
__global__ __launch_bounds__(256)
void row_pv(const float* __restrict__ attn, const f16* __restrict__ vbuf,
            float* __restrict__ rout)
{
    __shared__ float Ps[32][33];
    __shared__ float Vs[32][68];
    const int tid = threadIdx.x;
    const int tx = tid & 15, ty = tid >> 4;
    const int i0 = blockIdx.x * 32;
    const int h  = blockIdx.y;
    const int s  = blockIdx.z;
    const float* arow = attn + ((size_t)h * L_DIM + i0) * L_DIM;
    const int pr = tid >> 3, pc = (tid & 7) * 4;
    const int vr = tid >> 3, vc = (tid & 7) * 8;
    float acc[2][4] = {{0.f,0.f,0.f,0.f},{0.f,0.f,0.f,0.f}};

    for (int j0 = 0; j0 < L_DIM; j0 += 32) {
        float4 pv = *(const float4*)(arow + (size_t)pr * L_DIM + j0 + pc);
        union { float4 f; u16 u[8]; } vv;
        vv.f = *(const float4*)(vbuf + (size_t)(s * L_DIM + j0 + vr) * 768 + h*64 + vc);
        __syncthreads();
        Ps[pr][pc+0] = pv.x; Ps[pr][pc+1] = pv.y; Ps[pr][pc+2] = pv.z; Ps[pr][pc+3] = pv.w;
#pragma unroll
        for (int e = 0; e < 8; ++e) Vs[vr][vc+e] = h2f(vv.u[e]);
        __syncthreads();
#pragma unroll
        for (int jj = 0; jj < 32; ++jj) {
            float p0 = Ps[ty*2+0][jj];
            float p1 = Ps[ty*2+1][jj];
            float4 v4 = *(const float4*)&Vs[jj][tx*4];
            acc[0][0] += p0*v4.x; acc[0][1] += p0*v4.y; acc[0][2] += p0*v4.z; acc[0][3] += p0*v4.w;
            acc[1][0] += p1*v4.x; acc[1][1] += p1*v4.y; acc[1][2] += p1*v4.z; acc[1][3] += p1*v4.w;
        }
    }
#pragma unroll
    for (int a = 0; a < 2; ++a) {
        float4 o; o.x = acc[a][0]; o.y = acc[a][1]; o.z = acc[a][2]; o.w = acc[a][3];
        *(float4*)(rout + ((size_t)(s * L_DIM + i0 + ty*2 + a)) * D_DIM + h*64 + tx*4) = o;
    }
}

// ---------------------------------------------------------------------------
// out1_h = f16(LN(x + r)); x,r f32. grid NROW, block 256.
// ---------------------------------------------------------------------------
__global__ __launch_bounds__(256)
void add_ln_out16(const float* __restrict__ x, const float* __restrict__ r,
                  const float* __restrict__ g, const float* __restrict__ beta,
                  f16* __restrict__ out16)
{
    __shared__ float red[256];
    const int n = blockIdx.x, t = threadIdx.x;
    const float* xp = x + (size_t)n * D_DIM;
    const float* rp = r + (size_t)n * D_DIM;
    float v[3]; float s = 0.f;
#pragma unroll
    for (int e = 0; e < 3; ++e) { v[e] = xp[t + e*256] + rp[t + e*256]; s += v[e]; }
    red[t] = s; __syncthreads();
    for (int w = 128; w > 0; w >>= 1) { if (t < w) red[t] += red[t+w]; __syncthreads(); }
    float mean = red[0] * (1.f/768.f);
    __syncthreads();
    float sq = 0.f;
#pragma unroll
    for (int e = 0; e < 3; ++e) { float d = v[e] - mean; sq += d*d; }
    red[t] = sq; __syncthreads();
    for (int w = 128; w > 0; w >>= 1) { if (t < w) red[t] += red[t+w]; __syncthreads(); }
    float rstd = rsqrtf(red[0] * (1.f/768.f) + LN_EPS);
#pragma unroll
    for (int e = 0; e < 3; ++e) {
        int idx = t + e*256;
        out16[(size_t)n * D_DIM + idx] = (f16)((v[e] - mean) * rstd * g[idx] + beta[idx]);
    }
}

// ---------------------------------------------------------------------------
// out = LN(x16 + r) f32, in place on r. grid NROW, block 256.
// ---------------------------------------------------------------------------
__global__ __launch_bounds__(256)
void add_ln_in16(const f16* __restrict__ x16, float* __restrict__ r,
                 const float* __restrict__ g, const float* __restrict__ beta)
{
    __shared__ float red[256];
    const int n = blockIdx.x, t = threadIdx.x;
    const f16*   xp = x16 + (size_t)n * D_DIM;
    float*       rp = r   + (size_t)n * D_DIM;
    float v[3]; float s = 0.f;
#pragma unroll
    for (int e = 0; e < 3; ++e) { v[e] = (float)xp[t + e*256] + rp[t + e*256]; s += v[e]; }
    red[t] = s; __syncthreads();
    for (int w = 128; w > 0; w >>= 1) { if (t < w) red[t] += red[t+w]; __syncthreads(); }
    float mean = red[0] * (1.f/768.f);
    __syncthreads();
    float sq = 0.f;
#pragma unroll
    for (int e = 0; e < 3; ++e) { float d = v[e] - mean; sq += d*d; }
    red[t] = sq; __syncthreads();
    for (int w = 128; w > 0; w >>= 1) { if (t < w) red[t] += red[t+w]; __syncthreads(); }
    float rstd = rsqrtf(red[0] * (1.f/768.f) + LN_EPS);
#pragma unroll
    for (int e = 0; e < 3; ++e) {
        int idx = t + e*256;
        rp[idx] = (v[e] - mean) * rstd * g[idx] + beta[idx];
    }
}

// ---------------------------------------------------------------------------
// Column attention via MFMA. One block per (l,h): grid (256, 12), 256 thr =
// 4 waves; wave w owns i-rows [w*32, w*32+32).
//   QK^T: M=128(i) N=128(j) K=64(c), 16x16x32 f16 MFMA (layouts proven by
//   the GEMMs). Softmax over j done in-register on the C-layout: row
//   i = q*4+r lives in the 16 lm-lanes of quad q -> __shfl_xor(1,2,4,8).
//   exp (unnormalized) -> f16 Ps[i][j] (A-layout for PV), 1/sum deferred to
//   the PV epilogue (same lane holds the same i rows in both C-layouts).
//   PV: M=128(i) N=64(d) K=128(j), B = Vt[d][j] (transposed at load).
// LDS: Qs/Ks [128][72] (pad 72 -> stride 36 banks -> 2-way frag reads, free
// per m136); Ps [128][136] overlays Qs/Ks after QK; Vt [64][136].
// Total 54,272 B -> 3 blocks/CU (was 59,904 -> 2).
// ---------------------------------------------------------------------------
__global__ __launch_bounds__(256, 3)
void col_attn_mfma(const f16* __restrict__ p, float* __restrict__ cout)
{
    __shared__ char smem[54272];
    f16* Qs = (f16*)smem;             // [128][72]
    f16* Ks = (f16*)(smem + 18432);   // [128][72]
    f16* Ps = (f16*)smem;             // [128][136] overlay (after barrier)
    f16* Vt = (f16*)(smem + 36864);   // [64][136]

    const int tid  = threadIdx.x;
    const int lane = tid & 63;
    const int w    = tid >> 6;
    const int lm   = lane & 15;
    const int q    = lane >> 4;
    const int l = blockIdx.x, h = blockIdx.y;
    const int ib = w * 32;

    // ---- phase 1: stage Q,K row-major; V transposed into Vt[d][j]
    {
        const int r  = tid >> 1;          // s index 0..127
        const int hc = (tid & 1) * 32;    // c half
        const f16* rowp = p + (size_t)(r * 256 + l) * TD + h * 64 + hc;
#pragma unroll
        for (int cc = 0; cc < 4; ++cc)
            *(float4*)&Qs[r * 72 + hc + cc * 8] = *(const float4*)(rowp + cc * 8);
#pragma unroll
        for (int cc = 0; cc < 4; ++cc)
            *(float4*)&Ks[r * 72 + hc + cc * 8] = *(const float4*)(rowp + 768 + cc * 8);
#pragma unroll
        for (int cc = 0; cc < 4; ++cc) {
            union { float4 f; u16 u[8]; } vb;
            vb.f = *(const float4*)(rowp + 1536 + cc * 8);
#pragma unroll
            for (int e = 0; e < 8; ++e) {
                int d = hc + cc * 8 + e;
                ((u16*)Vt)[d * 136 + r] = vb.u[e];
            }
        }
    }
    __syncthreads();

    // ---- phase 2: S = Q K^T (wave tile 32x128: 2 mt x 8 nt x 2 ksteps)
    f32x4 acc[2][8];
#pragma unroll
    for (int mt = 0; mt < 2; ++mt)
#pragma unroll
        for (int nt = 0; nt < 8; ++nt) acc[mt][nt] = (f32x4)0.f;
#pragma unroll
    for (int ks = 0; ks < 2; ++ks) {
        f16x8 af[2];
#pragma unroll
        for (int mt = 0; mt < 2; ++mt)
            af[mt] = *(const f16x8*)&Qs[(ib + mt * 16 + lm) * 72 + ks * 32 + q * 8];
#pragma unroll
        for (int nt = 0; nt < 8; ++nt) {
            f16x8 bf = *(const f16x8*)&Ks[(nt * 16 + lm) * 72 + ks * 32 + q * 8];
#pragma unroll
            for (int mt = 0; mt < 2; ++mt)
                acc[mt][nt] = __builtin_amdgcn_mfma_f32_16x16x32_f16(
                    af[mt], bf, acc[mt][nt], 0, 0, 0);
        }
    }
    __syncthreads();   // all Qs/Ks frag reads done before Ps overlay writes

    // ---- phase 3: softmax over j in C-layout; write exp to Ps (f16)
    float inv_sum[2][4];
#pragma unroll
    for (int mt = 0; mt < 2; ++mt) {
#pragma unroll
        for (int r = 0; r < 4; ++r) {
            float m = acc[mt][0][r];
#pragma unroll
            for (int nt = 1; nt < 8; ++nt) m = fmaxf(m, acc[mt][nt][r]);
#pragma unroll
            for (int d = 1; d < 16; d <<= 1) m = fmaxf(m, __shfl_xor(m, d));
            float s = 0.f;
#pragma unroll
            for (int nt = 0; nt < 8; ++nt) {
                float e = __expf(acc[mt][nt][r] - m);
                acc[mt][nt][r] = e; s += e;
            }
#pragma unroll
            for (int d = 1; d < 16; d <<= 1) s += __shfl_xor(s, d);
            inv_sum[mt][r] = 1.f / s;
        }
        const int irow = ib + mt * 16 + q * 4;
#pragma unroll
        for (int nt = 0; nt < 8; ++nt) {
            const int jj = nt * 16 + lm;
#pragma unroll
            for (int r = 0; r < 4; ++r)
                Ps[(irow + r) * 136 + jj] = (f16)acc[mt][nt][r];
        }
    }
    __syncthreads();

    // ---- phase 4: O = P~ V (wave tile 32x64: 2 mt x 4 nt x 4 ksteps)
    f32x4 acc2[2][4];
#pragma unroll
    for (int mt = 0; mt < 2; ++mt)
#pragma unroll
        for (int nt = 0; nt < 4; ++nt) acc2[mt][nt] = (f32x4)0.f;
#pragma unroll
    for (int ks = 0; ks < 4; ++ks) {
        f16x8 pf[2];
#pragma unroll
        for (int mt = 0; mt < 2; ++mt)
            pf[mt] = *(const f16x8*)&Ps[(ib + mt * 16 + lm) * 136 + ks * 32 + q * 8];
#pragma unroll
        for (int nt = 0; nt < 4; ++nt) {
            f16x8 vf = *(const f16x8*)&Vt[(nt * 16 + lm) * 136 + ks * 32 + q * 8];
#pragma unroll
            for (int mt = 0; mt < 2; ++mt)
                acc2[mt][nt] = __builtin_amdgcn_mfma_f32_16x16x32_f16(
                    pf[mt], vf, acc2[mt][nt], 0, 0, 0);
        }
    }

    // ---- epilogue: apply deferred 1/sum, write f32
#pragma unroll
    for (int mt = 0; mt < 2; ++mt) {
        const int irow = ib + mt * 16 + q * 4;
#pragma unroll
        for (int nt = 0; nt < 4; ++nt) {
            const int d = nt * 16 + lm;
#pragma unroll
            for (int r = 0; r < 4; ++r)
                cout[(size_t)((irow + r) * 256 + l) * D_DIM + h * 64 + d] =
                    acc2[mt][nt][r] * inv_sum[mt][r];
        }
    }
}

// ---------------------------------------------------------------------------
extern "C" void kernel_launch(void* const* d_in, const int* in_sizes, int n_in,
                              void* d_out, int out_size, void* d_ws, size_t ws_size,
                              hipStream_t stream)
{
    const float* x     = (const float*)d_in[0];
    const float* w_row = (const float*)d_in[1];
    const float* b_row = (const float*)d_in[2];
    const float* w_col = (const float*)d_in[3];
    const float* b_col = (const float*)d_in[4];
    const float* g1    = (const float*)d_in[5];
    const float* be1   = (const float*)d_in[6];
    const float* g2    = (const float*)d_in[7];
    const float* be2   = (const float*)d_in[8];
    float* out = (float*)d_out;

    char* ws = (char*)d_ws;
    f16*   qt     = (f16*)(ws + WS_QT_OFF);
    f16*   kt     = (f16*)(ws + WS_KT_OFF);
    f16*   vbuf   = (f16*)(ws + WS_VB_OFF);
    f16*   p      = (f16*)(ws + WS_P_OFF);      // col phase, aliases qt/kt/vbuf
    float* lpart  = (float*)(ws + WS_LPART_OFF);
    float* logits = (float*)(ws + WS_LOGITS_OFF);
    f16*   xh     = (f16*)(ws + WS_XH_OFF);     // also out1_h after step 5
    f16*   wrh    = (f16*)(ws + WS_WRH_OFF);
    f16*   wch    = (f16*)(ws + WS_WCH_OFF);

    // 0) f32 -> f16 converts
    cvt_f32_f16<<<NROW * D_DIM / 1024, 256, 0, stream>>>(x, xh);
    cvt_f32_f16<<<TD * D_DIM / 1024, 256, 0, stream>>>(w_row, wrh);
    cvt_f32_f16<<<TD * D_DIM / 1024, 256, 0, stream>>>(w_col, wch);
    // 1) row QKV projection (MFMA) -> qt/kt (K-major) + vbuf
    mfma_gemm_row<<<dim3(TD/128, NROW/128), 256, 0, stream>>>(xh, wrh, b_row, qt, kt, vbuf);
    // 2) tied row logits (MFMA, split-K=4)
    row_logits_mfma<<<dim3(2, 2, 48), 256, 0, stream>>>(qt, kt, lpart);
    // 3) softmax over j (sums 4 partials)
    softmax256_4<<<H_DIM * L_DIM, 256, 0, stream>>>(lpart, logits);
    // 4) row PV -> d_out (scratch)
    row_pv<<<dim3(L_DIM/32, H_DIM, S_DIM), 256, 0, stream>>>(logits, vbuf, out);
    // 5) out1_h = f16(LN(x + row_out))  (xh dead; reuse as out1_h)
    add_ln_out16<<<NROW, 256, 0, stream>>>(x, out, g1, be1, xh);
    // 6) col QKV projection (MFMA) -> p (overwrites qt/kt/vbuf region)
    mfma_gemm_qkv<<<dim3(TD/128, NROW/128), 256, 0, stream>>>(xh, wch, b_col, p);
    // 7) column attention (MFMA) -> d_out (scratch)
    col_attn_mfma<<<dim3(L_DIM, H_DIM), 256, 0, stream>>>(p, out);
    // 8) out = LN(out1_h + col_out), in place on d_out
    add_ln_in16<<<NROW, 256, 0, stream>>>(xh, out, g2, be2);
}

// Round 6
// 761.626 us; speedup vs baseline: 5.0484x; 1.1983x over previous
//
#include <hip/hip_runtime.h>

// Problem constants (fixed by the reference): B=1
#define S_DIM 128
#define L_DIM 256
#define D_DIM 768
#define H_DIM 12
#define TD    2304            // 3*D
#define NROW  32768           // S*L
#define KDIM  768
#define LN_EPS 1e-5f

typedef unsigned short u16;
typedef unsigned int   u32;
typedef _Float16 f16;
typedef _Float16 f16x8 __attribute__((ext_vector_type(8)));
typedef _Float16 f16x4 __attribute__((ext_vector_type(4)));
typedef float    f32x4 __attribute__((ext_vector_type(4)));

// Workspace layout (bytes), total 224,133,120 (< 255 MB proven in rounds 1/2):
//  region R (151 MB, off 0) is time-multiplexed:
//    row phase : qt f16[H][L][8192] 50.33M | kt same | vt f16[H][8192][256] 50.33M
//    col phase : p  f16[NROW][TD]  151 MB   (GEMM2 overwrites; qt/kt/vt dead)
//  lpart  : f32 [4][H][L][L]  12,582,912   (split-K partials for row logits)
//  pt     : f16 [H][L][L]      1,572,864   (softmax probs, PV A-operand)
//  xh/u1h : f16 [NROW][D]     50,331,648
//  wr_h   : f16 [TD][D]        3,538,944
//  wc_h   : f16 [TD][D]        3,538,944
#define WS_QT_OFF     0
#define WS_KT_OFF     50331648
#define WS_VT_OFF     100663296
#define WS_P_OFF      0
#define WS_LPART_OFF  150994944
#define WS_PT_OFF     163577856
#define WS_XH_OFF     166723584
#define WS_WRH_OFF    217055232
#define WS_WCH_OFF    220594176

// fp16 staging (NOT bf16): row logits accumulate K=8192 products; bf16's
// 2^-9 rel-err gave final absmax 0.15 > 0.113 thr (round 1). fp16 passes
// at 0.047 (rounds 3-5) with fp16-input MFMA, fp32 accum.
__device__ __forceinline__ float h2f(u16 v) {
    union { u16 u; f16 h; } c; c.u = v; return (float)c.h;
}

__device__ __forceinline__ void gload_lds16(const void* g, void* l) {
    __builtin_amdgcn_global_load_lds((const __attribute__((address_space(1))) void*)g,
                                     (__attribute__((address_space(3))) void*)l, 16, 0, 0);
}

// ---------------------------------------------------------------------------
// f32 -> f16 convert, 4 elems/thread, grid sized exactly (n % 1024 == 0).
// ---------------------------------------------------------------------------
__global__ __launch_bounds__(256)
void cvt_f32_f16(const float* __restrict__ in, f16* __restrict__ out)
{
    int i = blockIdx.x * 256 + threadIdx.x;
    float4 v = ((const float4*)in)[i];
    f16x4 o; o.x = (f16)v.x; o.y = (f16)v.y; o.z = (f16)v.z; o.w = (f16)v.w;
    ((f16x4*)out)[i] = o;
}

// ---------------------------------------------------------------------------
// MFMA GEMM core (m97 pattern): 128x128 tile, BK=32, 256 thr = 4 waves (2x2
// of 64x64), each wave 4x4 of mfma_f32_16x16x32_f16. global_load_lds w=16;
// XOR chunk swizzle j ^= (m>>1)&3 keeps frag ds_read_b128 2-way (free, m136).
// ---------------------------------------------------------------------------
#define MFMA_PROLOG(KROW)                                                     \
    __shared__ f16 As[128 * 32];                                              \
    __shared__ f16 Bs[128 * 32];                                              \
    const int tid  = threadIdx.x;                                             \
    const int lane = tid & 63;                                                \
    const int w    = tid >> 6;                                                \
    const int wr   = (w >> 1) * 64;                                           \
    const int wc   = (w & 1) * 64;                                            \
    const int lm   = lane & 15;                                               \
    const int q    = lane >> 4;                                               \
    size_t soff[2];                                                           \
    int    ldsc[2];                                                           \
    _Pragma("unroll")                                                         \
    for (int t = 0; t < 2; ++t) {                                             \
        int c  = w * 128 + t * 64 + lane;                                     \
        int m  = c >> 2;                                                      \
        int gj = (c & 3) ^ ((m >> 1) & 3);                                    \
        soff[t] = (size_t)m * (KROW) + gj * 8;                                \
        ldsc[t] = (w * 128 + t * 64) * 8;                                     \
    }                                                                         \
    int chA[4], chB[4];                                                       \
    _Pragma("unroll")                                                         \
    for (int t = 0; t < 4; ++t) {                                             \
        int ma = wr + t * 16 + lm;                                            \
        chA[t] = ma * 4 + (q ^ ((ma >> 1) & 3));                              \
        int mb = wc + t * 16 + lm;                                            \
        chB[t] = mb * 4 + (q ^ ((mb >> 1) & 3));                              \
    }                                                                         \
    f32x4 acc[4][4];                                                          \
    _Pragma("unroll")                                                         \
    for (int i = 0; i < 4; ++i)                                               \
        _Pragma("unroll")                                                     \
        for (int j = 0; j < 4; ++j) acc[i][j] = (f32x4)0.f;

#define MFMA_KLOOP(baseA, baseB, KLEN)                                        \
    for (int k0 = 0; k0 < (KLEN); k0 += 32) {                                 \
        _Pragma("unroll")                                                     \
        for (int t = 0; t < 2; ++t) {                                         \
            gload_lds16((baseA) + soff[t] + k0, &As[ldsc[t]]);                \
            gload_lds16((baseB) + soff[t] + k0, &Bs[ldsc[t]]);                \
        }                                                                     \
        __syncthreads();                                                      \
        f16x8 af[4], bf[4];                                                   \
        _Pragma("unroll")                                                     \
        for (int t = 0; t < 4; ++t) af[t] = *(const f16x8*)&As[chA[t] * 8];   \
        _Pragma("unroll")                                                     \
        for (int t = 0; t < 4; ++t) bf[t] = *(const f16x8*)&Bs[chB[t] * 8];   \
        _Pragma("unroll")                                                     \
        for (int mt = 0; mt < 4; ++mt)                                        \
            _Pragma("unroll")                                                 \
            for (int nt = 0; nt < 4; ++nt)                                    \
                acc[mt][nt] = __builtin_amdgcn_mfma_f32_16x16x32_f16(         \
                    af[mt], bf[nt], acc[mt][nt], 0, 0, 0);                    \
        __syncthreads();                                                      \
    }

// ---------------------------------------------------------------------------
// GEMM2 (col QKV): C = A*W^T + bias -> p f16 [NROW][TD]. grid (18, 256).
// ---------------------------------------------------------------------------
__global__ __launch_bounds__(256)
void mfma_gemm_qkv(const f16* __restrict__ A, const f16* __restrict__ W,
                   const float* __restrict__ bias, f16* __restrict__ C)
{
    const int row0 = blockIdx.y * 128;
    const int col0 = blockIdx.x * 128;
    MFMA_PROLOG(KDIM)
    const f16* baseA = A + (size_t)row0 * KDIM;
    const f16* baseB = W + (size_t)col0 * KDIM;
    MFMA_KLOOP(baseA, baseB, KDIM)

    // C/D layout: col=lane&15, row=quad*4+reg
    float bv[4];
#pragma unroll
    for (int nt = 0; nt < 4; ++nt) bv[nt] = bias[col0 + wc + nt * 16 + lm];
#pragma unroll
    for (int mt = 0; mt < 4; ++mt) {
        int grow = row0 + wr + mt * 16 + q * 4;
#pragma unroll
        for (int nt = 0; nt < 4; ++nt) {
            int gcol = col0 + wc + nt * 16 + lm;
#pragma unroll
            for (int r = 0; r < 4; ++r)
                C[(size_t)(grow + r) * TD + gcol] = (f16)(acc[mt][nt][r] + bv[nt]);
        }
    }
}

// ---------------------------------------------------------------------------
// GEMM1 (row QKV): same GEMM but scatter epilogue:
//   q -> qt[h][i][s*64+c]       (K-major for the logits GEMM)
//   k -> kt[h][j][s*64+c]
//   v -> vt[h][s*64+d][j]       (K=j-major for the PV GEMM; r-consecutive
//                                accumulator elems = consecutive j -> f16x4)
// ---------------------------------------------------------------------------
__global__ __launch_bounds__(256)
void mfma_gemm_row(const f16* __restrict__ A, const f16* __restrict__ W,
                   const float* __restrict__ bias,
                   f16* __restrict__ qt, f16* __restrict__ kt,
                   f16* __restrict__ vt)
{
    const int row0 = blockIdx.y * 128;
    const int col0 = blockIdx.x * 128;
    MFMA_PROLOG(KDIM)
    const f16* baseA = A + (size_t)row0 * KDIM;
    const f16* baseB = W + (size_t)col0 * KDIM;
    MFMA_KLOOP(baseA, baseB, KDIM)

    if (col0 < 1536) {
        f16* dst = (col0 < 768) ? qt : kt;
        const int cbase = (col0 < 768) ? col0 : col0 - 768;
#pragma unroll
        for (int nt = 0; nt < 4; ++nt) {
            int gcol = cbase + wc + nt * 16 + lm;
            int h = gcol >> 6, c = gcol & 63;
            float b = bias[col0 + wc + nt * 16 + lm];
#pragma unroll
            for (int mt = 0; mt < 4; ++mt) {
                int n0 = row0 + wr + mt * 16 + q * 4;
#pragma unroll
                for (int r = 0; r < 4; ++r) {
                    int n = n0 + r;
                    int s = n >> 8, i = n & 255;
                    dst[(((size_t)h * 256 + i) * 128 + s) * 64 + c] =
                        (f16)(acc[mt][nt][r] + b);
                }
            }
        }
    } else {
#pragma unroll
        for (int nt = 0; nt < 4; ++nt) {
            int gcol = col0 + wc + nt * 16 + lm;
            int vcol = gcol - 1536;
            int h = vcol >> 6, d = vcol & 63;
            float b = bias[gcol];
#pragma unroll
            for (int mt = 0; mt < 4; ++mt) {
                int n0 = row0 + wr + mt * 16 + q * 4;
                int s = n0 >> 8, j0 = n0 & 255;   // r stays within one s
                f16x4 pack;
#pragma unroll
                for (int r = 0; r < 4; ++r) pack[r] = (f16)(acc[mt][nt][r] + b);
                *(f16x4*)&vt[((((size_t)h * 128 + s) * 64 + d) << 8) + j0] = pack;
            }
        }
    }
}

// ---------------------------------------------------------------------------
// Row logits via MFMA: split-K=4 partials. grid (2, 2, 48): z = h*4+sp.
// ---------------------------------------------------------------------------
__global__ __launch_bounds__(256)
void row_logits_mfma(const f16* __restrict__ qt, const f16* __restrict__ kt,
                     float* __restrict__ lpart)
{
    const int i0 = blockIdx.y * 128;
    const int j0 = blockIdx.x * 128;
    const int h  = blockIdx.z >> 2;
    const int sp = blockIdx.z & 3;
    MFMA_PROLOG(8192)
    const f16* baseA = qt + ((size_t)h * 256 + i0) * 8192 + sp * 2048;
    const f16* baseB = kt + ((size_t)h * 256 + j0) * 8192 + sp * 2048;
    MFMA_KLOOP(baseA, baseB, 2048)

    float* outp = lpart + (size_t)(sp * 12 + h) * 65536;
#pragma unroll
    for (int mt = 0; mt < 4; ++mt) {
        int grow = i0 + wr + mt * 16 + q * 4;
#pragma unroll
        for (int nt = 0; nt < 4; ++nt) {
            int gcol = j0 + wc + nt * 16 + lm;
#pragma unroll
            for (int r = 0; r < 4; ++r)
                outp[(size_t)(grow + r) * 256 + gcol] = acc[mt][nt][r];
        }
    }
}

// ---------------------------------------------------------------------------
// softmax over rows of 256, summing 4 split-K partials; probs out f16.
// grid = H*L, block 256.
// ---------------------------------------------------------------------------
__global__ __launch_bounds__(256)
void softmax256_4(const float* __restrict__ lpart, f16* __restrict__ pt)
{
    __shared__ float red[256];
    const int t = threadIdx.x;
    const size_t idx = (size_t)blockIdx.x * 256 + t;
    const size_t P = (size_t)12 * 65536;
    float v = lpart[idx] + lpart[idx + P] + lpart[idx + 2*P] + lpart[idx + 3*P];
    red[t] = v; __syncthreads();
    for (int w = 128; w > 0; w >>= 1) { if (t < w) red[t] = fmaxf(red[t], red[t+w]); __syncthreads(); }
    float m = red[0];
    __syncthreads();
    float e = __expf(v - m);
    red[t] = e; __syncthreads();
    for (int w = 128; w > 0; w >>= 1) { if (t < w) red[t] += red[t+w]; __syncthreads(); }
    pt[idx] = (f16)(e / red[0]);
}

// ---------------------------------------------------------------------------
// Row PV via MFMA: per h, out[i,(s,d)] = sum_j pt[h][i][j] * vt[h][(s,d)][j].
// M=256(i), N=8192(s*64+d), K=256(j). grid (64 ntiles, 2 mtiles, 12 h).
// Epilogue: rout[(s*256+i)*768 + h*64 + d], f32, 16-lane contiguous in d.
// ---------------------------------------------------------------------------
__global__ __launch_bounds__(256)
void row_pv_mfma(const f16* __restrict__ pt, const f16* __restrict__ vt,
                 float* __restrict__ rout)
{
    const int n0t = blockIdx.x * 128;
    const int i0  = blockIdx.y * 128;
    const int h   = blockIdx.z;
    MFMA_PROLOG(256)
    const f16* baseA = pt + (size_t)h * 65536 + (size_t)i0 * 256;
    const f16* baseB = vt + ((size_t)h * 8192 + n0t) * 256;
    MFMA_KLOOP(baseA, baseB, 256)

#pragma unroll
    for (int mt = 0; mt < 4; ++mt) {
        int irow = i0 + wr + mt * 16 + q * 4;
#pragma unroll
        for (int nt = 0; nt < 4; ++nt) {
            int n = n0t + wc + nt * 16 + lm;
            int s = n >> 6, d = n & 63;
#pragma unroll
            for (int r = 0; r < 4; ++r)
                rout[(size_t)(s * 256 + irow + r) * D_DIM + h * 64 + d] =
                    acc[mt][nt][r];
        }
    }
}

// ---------------------------------------------------------------------------
// out1_h = f16(LN(x + r)); x,r f32. grid NROW, block 256.
// ---------------------------------------------------------------------------
__global__ __launch_bounds__(256)
void add_ln_out16(const float* __restrict__ x, const float* __restrict__ r,
                  const float* __restrict__ g, const float* __restrict__ beta,
                  f16* __restrict__ out16)
{
    __shared__ float red[256];
    const int n = blockIdx.x, t = threadIdx.x;
    const float* xp = x + (size_t)n * D_DIM;
    const float* rp = r + (size_t)n * D_DIM;
    float v[3]; float s = 0.f;
#pragma unroll
    for (int e = 0; e < 3; ++e) { v[e] = xp[t + e*256] + rp[t + e*256]; s += v[e]; }
    red[t] = s; __syncthreads();
    for (int w = 128; w > 0; w >>= 1) { if (t < w) red[t] += red[t+w]; __syncthreads(); }
    float mean = red[0] * (1.f/768.f);
    __syncthreads();
    float sq = 0.f;
#pragma unroll
    for (int e = 0; e < 3; ++e) { float d = v[e] - mean; sq += d*d; }
    red[t] = sq; __syncthreads();
    for (int w = 128; w > 0; w >>= 1) { if (t < w) red[t] += red[t+w]; __syncthreads(); }
    float rstd = rsqrtf(red[0] * (1.f/768.f) + LN_EPS);
#pragma unroll
    for (int e = 0; e < 3; ++e) {
        int idx = t + e*256;
        out16[(size_t)n * D_DIM + idx] = (f16)((v[e] - mean) * rstd * g[idx] + beta[idx]);
    }
}

// ---------------------------------------------------------------------------
// out = LN(x16 + r) f32, in place on r. grid NROW, block 256.
// ---------------------------------------------------------------------------
__global__ __launch_bounds__(256)
void add_ln_in16(const f16* __restrict__ x16, float* __restrict__ r,
                 const float* __restrict__ g, const float* __restrict__ beta)
{
    __shared__ float red[256];
    const int n = blockIdx.x, t = threadIdx.x;
    const f16*   xp = x16 + (size_t)n * D_DIM;
    float*       rp = r   + (size_t)n * D_DIM;
    float v[3]; float s = 0.f;
#pragma unroll
    for (int e = 0; e < 3; ++e) { v[e] = (float)xp[t + e*256] + rp[t + e*256]; s += v[e]; }
    red[t] = s; __syncthreads();
    for (int w = 128; w > 0; w >>= 1) { if (t < w) red[t] += red[t+w]; __syncthreads(); }
    float mean = red[0] * (1.f/768.f);
    __syncthreads();
    float sq = 0.f;
#pragma unroll
    for (int e = 0; e < 3; ++e) { float d = v[e] - mean; sq += d*d; }
    red[t] = sq; __syncthreads();
    for (int w = 128; w > 0; w >>= 1) { if (t < w) red[t] += red[t+w]; __syncthreads(); }
    float rstd = rsqrtf(red[0] * (1.f/768.f) + LN_EPS);
#pragma unroll
    for (int e = 0; e < 3; ++e) {
        int idx = t + e*256;
        rp[idx] = (v[e] - mean) * rstd * g[idx] + beta[idx];
    }
}

// ---------------------------------------------------------------------------
// Column attention via MFMA. One block per (l,h): grid (256, 12), 256 thr =
// 4 waves; wave w owns i-rows [w*32, w*32+32). Softmax in-register on the
// C-layout (quad shuffles), 1/sum deferred to the PV epilogue.
// LDS: Qs/Ks [128][72]; Ps [128][136] overlays; Vt [64][136]. 54,272 B.
// ---------------------------------------------------------------------------
__global__ __launch_bounds__(256, 3)
void col_attn_mfma(const f16* __restrict__ p, float* __restrict__ cout)
{
    __shared__ char smem[54272];
    f16* Qs = (f16*)smem;             // [128][72]
    f16* Ks = (f16*)(smem + 18432);   // [128][72]
    f16* Ps = (f16*)smem;             // [128][136] overlay (after barrier)
    f16* Vt = (f16*)(smem + 36864);   // [64][136]

    const int tid  = threadIdx.x;
    const int lane = tid & 63;
    const int w    = tid >> 6;
    const int lm   = lane & 15;
    const int q    = lane >> 4;
    const int l = blockIdx.x, h = blockIdx.y;
    const int ib = w * 32;

    // ---- phase 1: stage Q,K row-major; V transposed into Vt[d][j]
    {
        const int r  = tid >> 1;          // s index 0..127
        const int hc = (tid & 1) * 32;    // c half
        const f16* rowp = p + (size_t)(r * 256 + l) * TD + h * 64 + hc;
#pragma unroll
        for (int cc = 0; cc < 4; ++cc)
            *(float4*)&Qs[r * 72 + hc + cc * 8] = *(const float4*)(rowp + cc * 8);
#pragma unroll
        for (int cc = 0; cc < 4; ++cc)
            *(float4*)&Ks[r * 72 + hc + cc * 8] = *(const float4*)(rowp + 768 + cc * 8);
#pragma unroll
        for (int cc = 0; cc < 4; ++cc) {
            union { float4 f; u16 u[8]; } vb;
            vb.f = *(const float4*)(rowp + 1536 + cc * 8);
#pragma unroll
            for (int e = 0; e < 8; ++e) {
                int d = hc + cc * 8 + e;
                ((u16*)Vt)[d * 136 + r] = vb.u[e];
            }
        }
    }
    __syncthreads();

    // ---- phase 2: S = Q K^T (wave tile 32x128: 2 mt x 8 nt x 2 ksteps)
    f32x4 acc[2][8];
#pragma unroll
    for (int mt = 0; mt < 2; ++mt)
#pragma unroll
        for (int nt = 0; nt < 8; ++nt) acc[mt][nt] = (f32x4)0.f;
#pragma unroll
    for (int ks = 0; ks < 2; ++ks) {
        f16x8 af[2];
#pragma unroll
        for (int mt = 0; mt < 2; ++mt)
            af[mt] = *(const f16x8*)&Qs[(ib + mt * 16 + lm) * 72 + ks * 32 + q * 8];
#pragma unroll
        for (int nt = 0; nt < 8; ++nt) {
            f16x8 bf = *(const f16x8*)&Ks[(nt * 16 + lm) * 72 + ks * 32 + q * 8];
#pragma unroll
            for (int mt = 0; mt < 2; ++mt)
                acc[mt][nt] = __builtin_amdgcn_mfma_f32_16x16x32_f16(
                    af[mt], bf, acc[mt][nt], 0, 0, 0);
        }
    }
    __syncthreads();   // all Qs/Ks frag reads done before Ps overlay writes

    // ---- phase 3: softmax over j in C-layout; write exp to Ps (f16)
    float inv_sum[2][4];
#pragma unroll
    for (int mt = 0; mt < 2; ++mt) {
#pragma unroll
        for (int r = 0; r < 4; ++r) {
            float m = acc[mt][0][r];
#pragma unroll
            for (int nt = 1; nt < 8; ++nt) m = fmaxf(m, acc[mt][nt][r]);
#pragma unroll
            for (int d = 1; d < 16; d <<= 1) m = fmaxf(m, __shfl_xor(m, d));
            float s = 0.f;
#pragma unroll
            for (int nt = 0; nt < 8; ++nt) {
                float e = __expf(acc[mt][nt][r] - m);
                acc[mt][nt][r] = e; s += e;
            }
#pragma unroll
            for (int d = 1; d < 16; d <<= 1) s += __shfl_xor(s, d);
            inv_sum[mt][r] = 1.f / s;
        }
        const int irow = ib + mt * 16 + q * 4;
#pragma unroll
        for (int nt = 0; nt < 8; ++nt) {
            const int jj = nt * 16 + lm;
#pragma unroll
            for (int r = 0; r < 4; ++r)
                Ps[(irow + r) * 136 + jj] = (f16)acc[mt][nt][r];
        }
    }
    __syncthreads();

    // ---- phase 4: O = P~ V (wave tile 32x64: 2 mt x 4 nt x 4 ksteps)
    f32x4 acc2[2][4];
#pragma unroll
    for (int mt = 0; mt < 2; ++mt)
#pragma unroll
        for (int nt = 0; nt < 4; ++nt) acc2[mt][nt] = (f32x4)0.f;
#pragma unroll
    for (int ks = 0; ks < 4; ++ks) {
        f16x8 pf[2];
#pragma unroll
        for (int mt = 0; mt < 2; ++mt)
            pf[mt] = *(const f16x8*)&Ps[(ib + mt * 16 + lm) * 136 + ks * 32 + q * 8];
#pragma unroll
        for (int nt = 0; nt < 4; ++nt) {
            f16x8 vf = *(const f16x8*)&Vt[(nt * 16 + lm) * 136 + ks * 32 + q * 8];
#pragma unroll
            for (int mt = 0; mt < 2; ++mt)
                acc2[mt][nt] = __builtin_amdgcn_mfma_f32_16x16x32_f16(
                    pf[mt], vf, acc2[mt][nt], 0, 0, 0);
        }
    }

    // ---- epilogue: apply deferred 1/sum, write f32
#pragma unroll
    for (int mt = 0; mt < 2; ++mt) {
        const int irow = ib + mt * 16 + q * 4;
#pragma unroll
        for (int nt = 0; nt < 4; ++nt) {
            const int d = nt * 16 + lm;
#pragma unroll
            for (int r = 0; r < 4; ++r)
                cout[(size_t)((irow + r) * 256 + l) * D_DIM + h * 64 + d] =
                    acc2[mt][nt][r] * inv_sum[mt][r];
        }
    }
}

// ---------------------------------------------------------------------------
extern "C" void kernel_launch(void* const* d_in, const int* in_sizes, int n_in,
                              void* d_out, int out_size, void* d_ws, size_t ws_size,
                              hipStream_t stream)
{
    const float* x     = (const float*)d_in[0];
    const float* w_row = (const float*)d_in[1];
    const float* b_row = (const float*)d_in[2];
    const float* w_col = (const float*)d_in[3];
    const float* b_col = (const float*)d_in[4];
    const float* g1    = (const float*)d_in[5];
    const float* be1   = (const float*)d_in[6];
    const float* g2    = (const float*)d_in[7];
    const float* be2   = (const float*)d_in[8];
    float* out = (float*)d_out;

    char* ws = (char*)d_ws;
    f16*   qt     = (f16*)(ws + WS_QT_OFF);
    f16*   kt     = (f16*)(ws + WS_KT_OFF);
    f16*   vt     = (f16*)(ws + WS_VT_OFF);
    f16*   p      = (f16*)(ws + WS_P_OFF);      // col phase, aliases qt/kt/vt
    float* lpart  = (float*)(ws + WS_LPART_OFF);
    f16*   pt     = (f16*)(ws + WS_PT_OFF);
    f16*   xh     = (f16*)(ws + WS_XH_OFF);     // also out1_h after step 5
    f16*   wrh    = (f16*)(ws + WS_WRH_OFF);
    f16*   wch    = (f16*)(ws + WS_WCH_OFF);

    // 0) f32 -> f16 converts
    cvt_f32_f16<<<NROW * D_DIM / 1024, 256, 0, stream>>>(x, xh);
    cvt_f32_f16<<<TD * D_DIM / 1024, 256, 0, stream>>>(w_row, wrh);
    cvt_f32_f16<<<TD * D_DIM / 1024, 256, 0, stream>>>(w_col, wch);
    // 1) row QKV projection (MFMA) -> qt/kt (K-major) + vt (j-major)
    mfma_gemm_row<<<dim3(TD/128, NROW/128), 256, 0, stream>>>(xh, wrh, b_row, qt, kt, vt);
    // 2) tied row logits (MFMA, split-K=4)
    row_logits_mfma<<<dim3(2, 2, 48), 256, 0, stream>>>(qt, kt, lpart);
    // 3) softmax over j (sums 4 partials) -> f16 probs
    softmax256_4<<<H_DIM * L_DIM, 256, 0, stream>>>(lpart, pt);
    // 4) row PV (MFMA) -> d_out (scratch)
    row_pv_mfma<<<dim3(64, 2, H_DIM), 256, 0, stream>>>(pt, vt, out);
    // 5) out1_h = f16(LN(x + row_out))  (xh dead; reuse as out1_h)
    add_ln_out16<<<NROW, 256, 0, stream>>>(x, out, g1, be1, xh);
    // 6) col QKV projection (MFMA) -> p (overwrites qt/kt/vt region)
    mfma_gemm_qkv<<<dim3(TD/128, NROW/128), 256, 0, stream>>>(xh, wch, b_col, p);
    // 7) column attention (MFMA) -> d_out (scratch)
    col_attn_mfma<<<dim3(L_DIM, H_DIM), 256, 0, stream>>>(p, out);
    // 8) out = LN(out1_h + col_out), in place on d_out
    add_ln_in16<<<NROW, 256, 0, stream>>>(xh, out, g2, be2);
}